// Round 9
// baseline (399.759 us; speedup 1.0000x reference)
//
#include <hip/hip_runtime.h>
#include <hip/hip_bf16.h>
#include <math.h>

#define B_ 2
#define S_ 2048
#define E_ 1024
#define H_ 16
#define D_ 64
#define TOK (B_*S_)          // 4096 tokens
// Q pre-scale folds sqrt(S) (reference quirk) and log2(e) so attn uses raw
// v_exp_f32 (base-2): softmax_2(x*log2e) == softmax_e(x), exactly.
#define SCALE2 (45.254833995939045f * 1.44269504088896340f)

typedef __bf16 bf16x8 __attribute__((ext_vector_type(8)));
typedef float floatx4 __attribute__((ext_vector_type(4)));
struct b4s { __hip_bfloat16 x, y, z, w; };   // 8-byte packed bf16 quad

typedef const __attribute__((address_space(1))) char ga_char;
typedef __attribute__((address_space(3))) char ls_char;

// async 16B/lane global->LDS copy; lds dest = wave-uniform base + lane*16
__device__ __forceinline__ void gload_lds16(const void* g, ls_char* l) {
  __builtin_amdgcn_global_load_lds((ga_char*)g, l, 16, 0, 0);
}

#if __has_builtin(__builtin_amdgcn_exp2f)
#define EXP2(x) __builtin_amdgcn_exp2f(x)
#else
#define EXP2(x) exp2f(x)
#endif

// XOR chunk swizzle for [64][32]-bf16 half-tiles
#define SWZ(arr, half, row, qpos) \
  (*(bf16x8*)&arr[half][row][(((qpos) ^ ((row) & 3)) * 8)])

// GEMM swizzle: chunk ^= (r&3)^((r>>2)&3) -> quarter-wave read phases hit
// each bank-group with only 2 lanes (free). +64-row staging needs no change
// (64 = 0 mod 4 in both row-bit fields).
__device__ __forceinline__ int gsw(int r) {
  return (r & 3) ^ ((r >> 2) & 3);
}

// ---------------------------------------------------------------------------
// All weight casts in ONE kernel.
// ---------------------------------------------------------------------------
__global__ __launch_bounds__(256) void cast_all(
    const float* __restrict__ Wfc, const float* __restrict__ W1,
    const float* __restrict__ W2, __hip_bfloat16* __restrict__ Wfcb,
    __hip_bfloat16* __restrict__ W1b, __hip_bfloat16* __restrict__ W2b,
    const float* __restrict__ Wq, const float* __restrict__ Wk,
    const float* __restrict__ Wv, __hip_bfloat16* __restrict__ Whl) {
  const int i = blockIdx.x * 256 + threadIdx.x;
  if (i < 2359296) {
    const float* src; __hip_bfloat16* dst; int j;
    if (i < 262144)       { src = Wfc; dst = Wfcb; j = i; }
    else if (i < 1310720) { src = W1;  dst = W1b;  j = i - 262144; }
    else                  { src = W2;  dst = W2b;  j = i - 1310720; }
    float4 v = ((const float4*)src)[j];
    b4s o;
    o.x = __float2bfloat16(v.x); o.y = __float2bfloat16(v.y);
    o.z = __float2bfloat16(v.z); o.w = __float2bfloat16(v.w);
    *(b4s*)(dst + (size_t)j * 4) = o;
  } else if (i < 2362368) {
    const int idx = i - 2359296;
    const int m = idx >> 10;
    const int off = (idx & 1023) * 4;
    const float* W = (m == 0) ? Wq : (m == 1) ? Wk : Wv;
    float4 v = *(const float4*)(W + off);
    b4s hi, lo;
    hi.x = __float2bfloat16(v.x); lo.x = __float2bfloat16(v.x - __bfloat162float(hi.x));
    hi.y = __float2bfloat16(v.y); lo.y = __float2bfloat16(v.y - __bfloat162float(hi.y));
    hi.z = __float2bfloat16(v.z); lo.z = __float2bfloat16(v.z - __bfloat162float(hi.z));
    hi.w = __float2bfloat16(v.w); lo.w = __float2bfloat16(v.w - __bfloat162float(hi.w));
    *(b4s*)(Whl + (size_t)m * 8192 + off) = hi;
    *(b4s*)(Whl + (size_t)m * 8192 + 4096 + off) = lo;
  }
}

// ---------------------------------------------------------------------------
// Fused QKV projection + hi/lo split + V transpose.
// Q output pre-scaled by SCALE2 = sqrt(S)*log2e.
// ---------------------------------------------------------------------------
__global__ __launch_bounds__(256) void qkv_fused(
    const float* __restrict__ xq, const float* __restrict__ xk,
    const float* __restrict__ xv, const __hip_bfloat16* __restrict__ Whl,
    __hip_bfloat16* __restrict__ qhi, __hip_bfloat16* __restrict__ qlo,
    __hip_bfloat16* __restrict__ khi, __hip_bfloat16* __restrict__ klo,
    __hip_bfloat16* __restrict__ vt) {
  __shared__ __bf16 Xh[2][64][32], Xl[2][64][32];
  __shared__ __bf16 Vt[64][72];
  const int t = threadIdx.x, lane = t & 63, w = t >> 6;
  const int quad = lane >> 4, low = lane & 15;
  const int bh = blockIdx.y;
  const int b = bh >> 4, h = bh & 15;
  const int s0 = blockIdx.x * 64;
  const int sr = t >> 2;
  const int sc = (t & 3) * 16;
  const int scc = sc >> 5;
  const int p0 = (sc & 31) >> 3;   // logical 16B chunk within half: 0 or 2

  for (int m = 0; m < 3; m++) {
    const float* xin = (m == 0) ? xq : (m == 1) ? xk : xv;
    const __hip_bfloat16* Wh = Whl + (size_t)m * 8192;
    const float sc_m = (m == 0) ? SCALE2 : 1.0f;

    __syncthreads();
    {
      const float* src = xin + ((size_t)(b * S_ + s0 + sr)) * E_ + h * 64 + sc;
      float4 f0 = *(const float4*)(src);
      float4 f1 = *(const float4*)(src + 4);
      float4 f2 = *(const float4*)(src + 8);
      float4 f3 = *(const float4*)(src + 12);
      float fv[16] = {f0.x, f0.y, f0.z, f0.w, f1.x, f1.y, f1.z, f1.w,
                      f2.x, f2.y, f2.z, f2.w, f3.x, f3.y, f3.z, f3.w};
      bf16x8 hi0, hi1, lo0, lo1;
      #pragma unroll
      for (int j = 0; j < 8; j++) {
        hi0[j] = (__bf16)fv[j];
        lo0[j] = (__bf16)(fv[j] - (float)hi0[j]);
        hi1[j] = (__bf16)fv[8 + j];
        lo1[j] = (__bf16)(fv[8 + j] - (float)hi1[j]);
      }
      SWZ(Xh, scc, sr, p0) = hi0;
      SWZ(Xh, scc, sr, p0 + 1) = hi1;
      SWZ(Xl, scc, sr, p0) = lo0;
      SWZ(Xl, scc, sr, p0 + 1) = lo1;
    }
    __syncthreads();

    bf16x8 ah[2], al[2];
    #pragma unroll
    for (int c = 0; c < 2; c++) {
      ah[c] = SWZ(Xh, c, w * 16 + low, quad);
      al[c] = SWZ(Xl, c, w * 16 + low, quad);
    }

    floatx4 acc[4];
    #pragma unroll
    for (int nn = 0; nn < 4; nn++) {
      floatx4 a = {};
      #pragma unroll
      for (int c = 0; c < 2; c++) {
        const __hip_bfloat16* wp = Wh + (nn * 16 + low) * 64 + c * 32 + quad * 8;
        bf16x8 wh_ = *(const bf16x8*)wp;
        bf16x8 wl_ = *(const bf16x8*)(wp + 4096);
        a = __builtin_amdgcn_mfma_f32_16x16x32_bf16(ah[c], wh_, a, 0, 0, 0);
        a = __builtin_amdgcn_mfma_f32_16x16x32_bf16(al[c], wh_, a, 0, 0, 0);
        a = __builtin_amdgcn_mfma_f32_16x16x32_bf16(ah[c], wl_, a, 0, 0, 0);
      }
      acc[nn] = a;
    }

    if (m < 2) {
      __hip_bfloat16* dh = (m == 0) ? qhi : khi;
      __hip_bfloat16* dl = (m == 0) ? qlo : klo;
      #pragma unroll
      for (int nn = 0; nn < 4; nn++) {
        #pragma unroll
        for (int i = 0; i < 4; i++) {
          const int s = s0 + w * 16 + quad * 4 + i;
          const int d = nn * 16 + low;
          const size_t adr = ((size_t)bh * S_ + s) * 64 + d;
          const float f = acc[nn][i] * sc_m;
          const __hip_bfloat16 hb = __float2bfloat16(f);
          dh[adr] = hb;
          dl[adr] = __float2bfloat16(f - __bfloat162float(hb));
        }
      }
    } else {
      #pragma unroll
      for (int nn = 0; nn < 4; nn++)
        #pragma unroll
        for (int i = 0; i < 4; i++)
          Vt[nn * 16 + low][w * 16 + quad * 4 + i] = (__bf16)acc[nn][i];
      __syncthreads();
      const int dr = t >> 2;
      const int scl = (t & 3) * 16;
      __hip_bfloat16* dst = vt + ((size_t)bh * 64 + dr) * S_ + s0 + scl;
      bf16x8 o0 = *(const bf16x8*)&Vt[dr][scl];
      bf16x8 o1 = *(const bf16x8*)&Vt[dr][scl + 8];
      *(bf16x8*)dst = o0;
      *(bf16x8*)(dst + 8) = o1;
    }
  }
}

// ---------------------------------------------------------------------------
// In-register online softmax (base 2) + pack PV B-fragments.
// ---------------------------------------------------------------------------
__device__ __forceinline__ void softmax_update(
    const floatx4* sa, floatx4* oacc, float& mrow, float& lrow, bf16x8* pb) {
  float rmax;
  {
    float m0 = fmaxf(fmaxf(sa[0][0], sa[0][1]), fmaxf(sa[0][2], sa[0][3]));
    float m1 = fmaxf(fmaxf(sa[1][0], sa[1][1]), fmaxf(sa[1][2], sa[1][3]));
    float m2 = fmaxf(fmaxf(sa[2][0], sa[2][1]), fmaxf(sa[2][2], sa[2][3]));
    float m3 = fmaxf(fmaxf(sa[3][0], sa[3][1]), fmaxf(sa[3][2], sa[3][3]));
    rmax = fmaxf(fmaxf(m0, m1), fmaxf(m2, m3));
    rmax = fmaxf(rmax, __shfl_xor(rmax, 16, 64));
    rmax = fmaxf(rmax, __shfl_xor(rmax, 32, 64));
  }
  if (__any(rmax > mrow)) {           // T13: skip rescale when max static
    const float nm = fmaxf(mrow, rmax);
    const float al = EXP2(mrow - nm);
    mrow = nm;
    lrow *= al;
    #pragma unroll
    for (int dt = 0; dt < 4; dt++) {
      oacc[dt][0] *= al; oacc[dt][1] *= al;
      oacc[dt][2] *= al; oacc[dt][3] *= al;
    }
  }
  float p[4][4];
  float rs;
  {
    float r0_ = 0.f, r1_ = 0.f, r2_ = 0.f, r3_ = 0.f;
    #pragma unroll
    for (int i = 0; i < 4; i++) {
      p[0][i] = EXP2(sa[0][i] - mrow); r0_ += p[0][i];
      p[1][i] = EXP2(sa[1][i] - mrow); r1_ += p[1][i];
      p[2][i] = EXP2(sa[2][i] - mrow); r2_ += p[2][i];
      p[3][i] = EXP2(sa[3][i] - mrow); r3_ += p[3][i];
    }
    rs = (r0_ + r1_) + (r2_ + r3_);
    rs += __shfl_xor(rs, 16, 64);
    rs += __shfl_xor(rs, 32, 64);
  }
  lrow += rs;
  // pb[khalf][j] = P[k = khalf*32 + quad*8 + j][q]
  #pragma unroll
  for (int kh2 = 0; kh2 < 2; kh2++) {
    bf16x8 v;
    v[0] = (__bf16)p[kh2][0]; v[1] = (__bf16)p[kh2][1];
    v[2] = (__bf16)p[kh2][2]; v[3] = (__bf16)p[kh2][3];
    v[4] = (__bf16)p[kh2 + 2][0]; v[5] = (__bf16)p[kh2 + 2][1];
    v[6] = (__bf16)p[kh2 + 2][2]; v[7] = (__bf16)p[kh2 + 2][3];
    pb[kh2] = v;
  }
}

// ---------------------------------------------------------------------------
// MFMA flash attention — R5 structure (best known ~87.5-90us; converged).
// LDS staging is load-bearing (R6: 358us without it).
// ---------------------------------------------------------------------------
__global__ __launch_bounds__(512, 4) void attn_mfma(
    const __hip_bfloat16* __restrict__ Qhi, const __hip_bfloat16* __restrict__ Qlo,
    const __hip_bfloat16* __restrict__ Khi, const __hip_bfloat16* __restrict__ Klo,
    const __hip_bfloat16* __restrict__ Vtg, __hip_bfloat16* __restrict__ ctx) {
  __shared__ __bf16 Kh[2][2][64][32], Kl[2][2][64][32], Vs[2][2][64][32];
  const int t = threadIdx.x, lane = t & 63, w = t >> 6;   // w: 0..7
  const int quad = lane >> 4, low = lane & 15;
  const int bh = blockIdx.x;                  // bh fastest: q-tiles of one bh
  const int qw = blockIdx.y * 128 + w * 16;   // share an XCD's L2 for K/V

  const int sh = w >> 2;
  const int r0 = (w & 3) * 16;
  const int srow = r0 + (lane >> 2);            // 0..63
  const int sq = (lane & 3) ^ (srow & 3);       // pre-swizzled chunk
  const __hip_bfloat16* gK = Khi + ((size_t)bh * S_ + srow) * 64 + sh * 32 + sq * 8;
  const __hip_bfloat16* gL = Klo + ((size_t)bh * S_ + srow) * 64 + sh * 32 + sq * 8;
  const __hip_bfloat16* gV = Vtg + ((size_t)bh * 64 + srow) * S_ + sh * 32 + sq * 8;

  // Q fragments straight from global (pre-scaled by SCALE2 in qkv_fused)
  bf16x8 qh[2], ql[2];
  {
    const size_t qbase = ((size_t)bh * S_ + qw + low) * 64 + quad * 8;
    qh[0] = *(const bf16x8*)(Qhi + qbase);
    qh[1] = *(const bf16x8*)(Qhi + qbase + 32);
    ql[0] = *(const bf16x8*)(Qlo + qbase);
    ql[1] = *(const bf16x8*)(Qlo + qbase + 32);
  }

  floatx4 oacc[4] = {};
  float mrow = -3e38f, lrow = 0.f;

  // prefetch tile 0 into buf 0
  gload_lds16(gK, (ls_char*)&Kh[0][sh][r0][0]);
  gload_lds16(gL, (ls_char*)&Kl[0][sh][r0][0]);
  gload_lds16(gV, (ls_char*)&Vs[0][sh][r0][0]);

  for (int kt = 0; kt < S_ / 64; kt++) {
    const int cur = kt & 1;
    __syncthreads();   // drains gload_lds (vmcnt) + publishes buf `cur`
    if (kt + 1 < S_ / 64) {
      gload_lds16(gK + (size_t)(kt + 1) * 4096, (ls_char*)&Kh[cur ^ 1][sh][r0][0]);
      gload_lds16(gL + (size_t)(kt + 1) * 4096, (ls_char*)&Kl[cur ^ 1][sh][r0][0]);
      gload_lds16(gV + (size_t)(kt + 1) * 64,   (ls_char*)&Vs[cur ^ 1][sh][r0][0]);
    }

    // QK^T swapped: sa[nn][i] = S[k = (nn&1)*32 + quad*8 + (nn>>1)*4 + i][q]
    floatx4 sa[4];
    __builtin_amdgcn_s_setprio(1);
    #pragma unroll
    for (int nn = 0; nn < 4; nn++) {
      const int prow = (nn & 1) * 32 + (nn >> 1) * 4 + (low >> 2) * 8 + (low & 3);
      bf16x8 kh0 = SWZ(Kh[cur], 0, prow, quad);
      bf16x8 kh1 = SWZ(Kh[cur], 1, prow, quad);
      bf16x8 kl0 = SWZ(Kl[cur], 0, prow, quad);
      bf16x8 kl1 = SWZ(Kl[cur], 1, prow, quad);
      floatx4 s = {};
      s = __builtin_amdgcn_mfma_f32_16x16x32_bf16(kh0, qh[0], s, 0, 0, 0);
      s = __builtin_amdgcn_mfma_f32_16x16x32_bf16(kh1, qh[1], s, 0, 0, 0);
      s = __builtin_amdgcn_mfma_f32_16x16x32_bf16(kl0, qh[0], s, 0, 0, 0);
      s = __builtin_amdgcn_mfma_f32_16x16x32_bf16(kl1, qh[1], s, 0, 0, 0);
      s = __builtin_amdgcn_mfma_f32_16x16x32_bf16(kh0, ql[0], s, 0, 0, 0);
      s = __builtin_amdgcn_mfma_f32_16x16x32_bf16(kh1, ql[1], s, 0, 0, 0);
      sa[nn] = s;
    }
    __builtin_amdgcn_s_setprio(0);

    bf16x8 pb[2];
    softmax_update(sa, oacc, mrow, lrow, pb);

    // PV: oacc[dt] = O^T rows d = dt*16 + quad*4 + i, col q = qw + low
    __builtin_amdgcn_s_setprio(1);
    #pragma unroll
    for (int dt = 0; dt < 4; dt++) {
      bf16x8 vb0 = SWZ(Vs[cur], 0, dt * 16 + low, quad);
      bf16x8 vb1 = SWZ(Vs[cur], 1, dt * 16 + low, quad);
      oacc[dt] = __builtin_amdgcn_mfma_f32_16x16x32_bf16(vb0, pb[0], oacc[dt], 0, 0, 0);
      oacc[dt] = __builtin_amdgcn_mfma_f32_16x16x32_bf16(vb1, pb[1], oacc[dt], 0, 0, 0);
    }
    __builtin_amdgcn_s_setprio(0);
  }

  const float inv = 1.0f / lrow;
  const int b = bh >> 4, h = bh & 15;
  const size_t base = ((size_t)(b * S_ + qw + low)) * E_ + h * 64 + quad * 4;
  #pragma unroll
  for (int dt = 0; dt < 4; dt++) {
    b4s o;
    o.x = __float2bfloat16(oacc[dt][0] * inv);
    o.y = __float2bfloat16(oacc[dt][1] * inv);
    o.z = __float2bfloat16(oacc[dt][2] * inv);
    o.w = __float2bfloat16(oacc[dt][3] * inv);
    *(b4s*)(ctx + base + dt * 16) = o;
  }
}

// ---------------------------------------------------------------------------
// bf16 MFMA GEMM, round 16: BK=32 double-buffer. 2-phase kept, but LDS cut
// 64KB->16KB so occupancy doubles to 4 blocks/CU = 16 waves/CU (the TLP
// point that has won everywhere this session; m97 evidence: BK=32 + high
// TLP = 874 TF even with more barriers). gsw swizzle: 2-way bank access.
// ---------------------------------------------------------------------------
template <int RELU, int OUT_BF16, int PARTIAL>
__global__ __launch_bounds__(256, 4) void gemm_mfma(
    const __hip_bfloat16* __restrict__ A, const __hip_bfloat16* __restrict__ Wt,
    const float* __restrict__ bias, void* __restrict__ C0, void* __restrict__ C1,
    int M, int N, int Kblk, int lda) {
  __shared__ __bf16 As[2][128][32];
  __shared__ __bf16 Bs[2][128][32];
  const int t = threadIdx.x;
  const int lane = t & 63;
  const int w = t >> 6;
  const int wr = w >> 1, wc = w & 1;
  const int m0 = blockIdx.y * 128, n0 = blockIdx.x * 128;
  void* Cout = (blockIdx.z == 0) ? C0 : C1;

  A += (size_t)blockIdx.z * Kblk;
  Wt += (size_t)blockIdx.z * Kblk;

  floatx4 acc[4][4] = {};
  const int srow = t >> 2;                      // 0..63
  const int ssc = ((t & 3) ^ gsw(srow)) * 8;    // pre-swizzled source chunk

  const __hip_bfloat16* gA = A + (size_t)(m0 + srow) * lda + ssc;
  const __hip_bfloat16* gB = Wt + (size_t)(n0 + srow) * lda + ssc;
  const size_t rstep = (size_t)64 * lda;        // rows 64..127 (gsw(r+64)==gsw(r))

#define GSTAGE(buf, k0) do {                                      \
    ls_char* lA = (ls_char*)&As[buf][0][0] + w * 1024;            \
    ls_char* lB = (ls_char*)&Bs[buf][0][0] + w * 1024;            \
    gload_lds16(gA + (k0),         lA);                           \
    gload_lds16(gA + (k0) + rstep, lA + 4096);                    \
    gload_lds16(gB + (k0),         lB);                           \
    gload_lds16(gB + (k0) + rstep, lB + 4096);                    \
  } while (0)

  GSTAGE(0, 0);                    // prologue prefetch
  const int nsteps = Kblk >> 5;
  for (int st = 0; st < nsteps; st++) {
    const int cur = st & 1;
    __syncthreads();               // drains vmcnt for buf `cur`; publishes it
    if (st + 1 < nsteps) GSTAGE(cur ^ 1, (st + 1) * 32);

    bf16x8 af[4], bfr[4];
    #pragma unroll
    for (int i = 0; i < 4; i++) {
      const int ra = wr * 64 + i * 16 + (lane & 15);
      af[i] = *(const bf16x8*)&As[cur][ra][(((lane >> 4) ^ gsw(ra)) * 8)];
      const int rb = wc * 64 + i * 16 + (lane & 15);
      bfr[i] = *(const bf16x8*)&Bs[cur][rb][(((lane >> 4) ^ gsw(rb)) * 8)];
    }
    #pragma unroll
    for (int mi = 0; mi < 4; mi++)
      #pragma unroll
      for (int ni = 0; ni < 4; ni++)
        acc[mi][ni] = __builtin_amdgcn_mfma_f32_16x16x32_bf16(
            af[mi], bfr[ni], acc[mi][ni], 0, 0, 0);
  }
#undef GSTAGE

  const int cil = lane & 15;
  const int quad = lane >> 4;
  #pragma unroll
  for (int ni = 0; ni < 4; ni++) {
    const int col = n0 + wc * 64 + ni * 16 + cil;
    const float bb = PARTIAL ? 0.f : bias[col];
    #pragma unroll
    for (int mi = 0; mi < 4; mi++) {
      const int row = m0 + wr * 64 + mi * 16 + quad * 4;
      #pragma unroll
      for (int i = 0; i < 4; i++) {
        if (PARTIAL) {
          ((float*)Cout)[(size_t)(row + i) * N + col] = acc[mi][ni][i];
        } else {
          float vv = acc[mi][ni][i] + bb;
          if (RELU) vv = fmaxf(vv, 0.f);
          if (OUT_BF16)
            ((__hip_bfloat16*)Cout)[(size_t)(row + i) * N + col] = __float2bfloat16(vv);
          else
            ((float*)Cout)[(size_t)(row + i) * N + col] = vv;
        }
      }
    }
  }
}

// ---------------------------------------------------------------------------
// out = LayerNorm(a0 [+ a1] [+ bias] + r)*g + b ; optional secondary bf16 out.
// ---------------------------------------------------------------------------
template <int EMIT_BF16, int HAS_A1, int HAS_BIAS>
__global__ __launch_bounds__(256) void add_ln(
    const float* __restrict__ a0, const float* __restrict__ a1,
    const float* __restrict__ r, const float* __restrict__ bias,
    const float* __restrict__ g, const float* __restrict__ bt,
    float* __restrict__ out, __hip_bfloat16* __restrict__ outb) {
  __shared__ float red[16];
  const int tok = blockIdx.x, t = threadIdx.x;
  float4 av = ((const float4*)(a0 + (size_t)tok * E_))[t];
  float4 rv = ((const float4*)(r + (size_t)tok * E_))[t];
  float4 x;
  x.x = av.x + rv.x; x.y = av.y + rv.y; x.z = av.z + rv.z; x.w = av.w + rv.w;
  if (HAS_A1) {
    float4 a2 = ((const float4*)(a1 + (size_t)tok * E_))[t];
    x.x += a2.x; x.y += a2.y; x.z += a2.z; x.w += a2.w;
  }
  if (HAS_BIAS) {
    float4 cv = ((const float4*)bias)[t];
    x.x += cv.x; x.y += cv.y; x.z += cv.z; x.w += cv.w;
  }
  float sum = x.x + x.y + x.z + x.w;
  float ssq = x.x * x.x + x.y * x.y + x.z * x.z + x.w * x.w;
  #pragma unroll
  for (int off = 32; off >= 1; off >>= 1) {
    sum += __shfl_down(sum, off, 64);
    ssq += __shfl_down(ssq, off, 64);
  }
  const int wave = t >> 6;
  if ((t & 63) == 0) { red[wave] = sum; red[4 + wave] = ssq; }
  __syncthreads();
  if (t == 0) {
    float s = red[0] + red[1] + red[2] + red[3];
    float qq = red[4] + red[5] + red[6] + red[7];
    float mu = s * (1.0f / E_);
    red[8] = mu;
    red[9] = qq * (1.0f / E_) - mu * mu;
  }
  __syncthreads();
  const float mu = red[8];
  const float inv = rsqrtf(red[9] + 1e-5f);
  float4 gv = ((const float4*)g)[t];
  float4 bv = ((const float4*)bt)[t];
  float4 o;
  o.x = (x.x - mu) * inv * gv.x + bv.x;
  o.y = (x.y - mu) * inv * gv.y + bv.y;
  o.z = (x.z - mu) * inv * gv.z + bv.z;
  o.w = (x.w - mu) * inv * gv.w + bv.w;
  ((float4*)(out + (size_t)tok * E_))[t] = o;
  if (EMIT_BF16) {
    b4s ob;
    ob.x = __float2bfloat16(o.x); ob.y = __float2bfloat16(o.y);
    ob.z = __float2bfloat16(o.z); ob.w = __float2bfloat16(o.w);
    *(b4s*)(outb + (size_t)tok * E_ + t * 4) = ob;
  }
}

// ---------------------------------------------------------------------------
extern "C" void kernel_launch(void* const* d_in, const int* in_sizes, int n_in,
                              void* d_out, int out_size, void* d_ws, size_t ws_size,
                              hipStream_t stream) {
  const float* queries = (const float*)d_in[0];
  const float* keys    = (const float*)d_in[1];
  const float* values  = (const float*)d_in[2];
  const float* Wq  = (const float*)d_in[4];
  const float* Wk  = (const float*)d_in[5];
  const float* Wv  = (const float*)d_in[6];
  const float* Wfc = (const float*)d_in[7];
  const float* bfc = (const float*)d_in[8];
  const float* W1  = (const float*)d_in[9];
  const float* b1  = (const float*)d_in[10];
  const float* W2  = (const float*)d_in[11];
  const float* b2  = (const float*)d_in[12];
  const float* ln1_g = (const float*)d_in[13];
  const float* ln1_b = (const float*)d_in[14];
  const float* ln2_g = (const float*)d_in[15];
  const float* ln2_b = (const float*)d_in[16];

  const size_t M1 = 1048576;
  float* ws = (float*)d_ws;
  float* P0  = ws;             // 4M fl: split-K partial 0
  float* P1  = ws + 4 * M1;    // 4M fl: split-K partial 1
  float* Hf  = ws + 8 * M1;    // 4M fl
  __hip_bfloat16* bb = (__hip_bfloat16*)(ws + 12 * M1);
  __hip_bfloat16* CTXb = bb;                  //  4M
  __hip_bfloat16* Hb   = bb + 4 * M1;         //  4M
  __hip_bfloat16* Wfcb = bb + 8 * M1;         //  1M
  __hip_bfloat16* W1b  = bb + 9 * M1;         //  4M
  __hip_bfloat16* W2b  = bb + 13 * M1;        //  4M
  // attention temps (17M..37M) alias FF1b (17M..33M): FF1b written after attn
  __hip_bfloat16* Qhi  = bb + 17 * M1;        //  4M
  __hip_bfloat16* Qlo  = bb + 21 * M1;        //  4M
  __hip_bfloat16* Khi  = bb + 25 * M1;        //  4M
  __hip_bfloat16* Klo  = bb + 29 * M1;        //  4M
  __hip_bfloat16* Vtb  = bb + 33 * M1;        //  4M
  __hip_bfloat16* FF1b = bb + 17 * M1;        // 16M (after attention)
  __hip_bfloat16* Whlb = bb + 37 * M1;        // 24K
  float* out = (float*)d_out;

  cast_all<<<9228, 256, 0, stream>>>(Wfc, W1, W2, Wfcb, W1b, W2b,
                                     Wq, Wk, Wv, Whlb);

  qkv_fused<<<dim3(S_ / 64, B_ * H_), 256, 0, stream>>>(
      queries, keys, values, Whlb, Qhi, Qlo, Khi, Klo, Vtb);
  attn_mfma<<<dim3(B_ * H_, S_ / 128), 512, 0, stream>>>(
      Qhi, Qlo, Khi, Klo, Vtb, CTXb);
  gemm_mfma<0, 0, 1><<<dim3(E_ / 128, TOK / 128, 2), 256, 0, stream>>>(
      CTXb, Wfcb, nullptr, P0, P1, TOK, E_, 512, E_);
  add_ln<1, 1, 1><<<TOK, 256, 0, stream>>>(
      P0, P1, queries, bfc, ln1_g, ln1_b, Hf, Hb);
  gemm_mfma<1, 1, 0><<<dim3(4 * E_ / 128, TOK / 128, 1), 256, 0, stream>>>(
      Hb, W1b, b1, FF1b, nullptr, TOK, 4 * E_, E_, E_);
  gemm_mfma<0, 0, 1><<<dim3(E_ / 128, TOK / 128, 2), 256, 0, stream>>>(
      FF1b, W2b, nullptr, P0, P1, TOK, E_, 2048, 4 * E_);
  add_ln<0, 1, 1><<<TOK, 256, 0, stream>>>(
      P0, P1, Hf, b2, ln2_g, ln2_b, out, nullptr);
}

// Round 10
// 389.037 us; speedup vs baseline: 1.0276x; 1.0276x over previous
//
#include <hip/hip_runtime.h>
#include <hip/hip_bf16.h>
#include <math.h>

#define B_ 2
#define S_ 2048
#define E_ 1024
#define H_ 16
#define D_ 64
#define TOK (B_*S_)          // 4096 tokens
// Q pre-scale folds sqrt(S) (reference quirk) and log2(e) so attn uses raw
// v_exp_f32 (base-2): softmax_2(x*log2e) == softmax_e(x), exactly.
#define SCALE2 (45.254833995939045f * 1.44269504088896340f)

typedef __bf16 bf16x8 __attribute__((ext_vector_type(8)));
typedef float floatx4 __attribute__((ext_vector_type(4)));
struct b4s { __hip_bfloat16 x, y, z, w; };   // 8-byte packed bf16 quad

typedef const __attribute__((address_space(1))) char ga_char;
typedef __attribute__((address_space(3))) char ls_char;

// async 16B/lane global->LDS copy; lds dest = wave-uniform base + lane*16
__device__ __forceinline__ void gload_lds16(const void* g, ls_char* l) {
  __builtin_amdgcn_global_load_lds((ga_char*)g, l, 16, 0, 0);
}

#if __has_builtin(__builtin_amdgcn_exp2f)
#define EXP2(x) __builtin_amdgcn_exp2f(x)
#else
#define EXP2(x) exp2f(x)
#endif

// XOR chunk swizzle for [64][32]-bf16 half-tiles
#define SWZ(arr, half, row, qpos) \
  (*(bf16x8*)&arr[half][row][(((qpos) ^ ((row) & 3)) * 8)])

// raw workgroup barrier, fenced so memory ops can't cross it
__device__ __forceinline__ void sbar() {
  asm volatile("" ::: "memory");
  __builtin_amdgcn_s_barrier();
  asm volatile("" ::: "memory");
}

// ---------------------------------------------------------------------------
// All weight casts in ONE kernel.
// ---------------------------------------------------------------------------
__global__ __launch_bounds__(256) void cast_all(
    const float* __restrict__ Wfc, const float* __restrict__ W1,
    const float* __restrict__ W2, __hip_bfloat16* __restrict__ Wfcb,
    __hip_bfloat16* __restrict__ W1b, __hip_bfloat16* __restrict__ W2b,
    const float* __restrict__ Wq, const float* __restrict__ Wk,
    const float* __restrict__ Wv, __hip_bfloat16* __restrict__ Whl) {
  const int i = blockIdx.x * 256 + threadIdx.x;
  if (i < 2359296) {
    const float* src; __hip_bfloat16* dst; int j;
    if (i < 262144)       { src = Wfc; dst = Wfcb; j = i; }
    else if (i < 1310720) { src = W1;  dst = W1b;  j = i - 262144; }
    else                  { src = W2;  dst = W2b;  j = i - 1310720; }
    float4 v = ((const float4*)src)[j];
    b4s o;
    o.x = __float2bfloat16(v.x); o.y = __float2bfloat16(v.y);
    o.z = __float2bfloat16(v.z); o.w = __float2bfloat16(v.w);
    *(b4s*)(dst + (size_t)j * 4) = o;
  } else if (i < 2362368) {
    const int idx = i - 2359296;
    const int m = idx >> 10;
    const int off = (idx & 1023) * 4;
    const float* W = (m == 0) ? Wq : (m == 1) ? Wk : Wv;
    float4 v = *(const float4*)(W + off);
    b4s hi, lo;
    hi.x = __float2bfloat16(v.x); lo.x = __float2bfloat16(v.x - __bfloat162float(hi.x));
    hi.y = __float2bfloat16(v.y); lo.y = __float2bfloat16(v.y - __bfloat162float(hi.y));
    hi.z = __float2bfloat16(v.z); lo.z = __float2bfloat16(v.z - __bfloat162float(hi.z));
    hi.w = __float2bfloat16(v.w); lo.w = __float2bfloat16(v.w - __bfloat162float(hi.w));
    *(b4s*)(Whl + (size_t)m * 8192 + off) = hi;
    *(b4s*)(Whl + (size_t)m * 8192 + 4096 + off) = lo;
  }
}

// ---------------------------------------------------------------------------
// Fused QKV projection + hi/lo split + V transpose.
// Q output pre-scaled by SCALE2 = sqrt(S)*log2e.
// ---------------------------------------------------------------------------
__global__ __launch_bounds__(256) void qkv_fused(
    const float* __restrict__ xq, const float* __restrict__ xk,
    const float* __restrict__ xv, const __hip_bfloat16* __restrict__ Whl,
    __hip_bfloat16* __restrict__ qhi, __hip_bfloat16* __restrict__ qlo,
    __hip_bfloat16* __restrict__ khi, __hip_bfloat16* __restrict__ klo,
    __hip_bfloat16* __restrict__ vt) {
  __shared__ __bf16 Xh[2][64][32], Xl[2][64][32];
  __shared__ __bf16 Vt[64][72];
  const int t = threadIdx.x, lane = t & 63, w = t >> 6;
  const int quad = lane >> 4, low = lane & 15;
  const int bh = blockIdx.y;
  const int b = bh >> 4, h = bh & 15;
  const int s0 = blockIdx.x * 64;
  const int sr = t >> 2;
  const int sc = (t & 3) * 16;
  const int scc = sc >> 5;
  const int p0 = (sc & 31) >> 3;   // logical 16B chunk within half: 0 or 2

  for (int m = 0; m < 3; m++) {
    const float* xin = (m == 0) ? xq : (m == 1) ? xk : xv;
    const __hip_bfloat16* Wh = Whl + (size_t)m * 8192;
    const float sc_m = (m == 0) ? SCALE2 : 1.0f;

    __syncthreads();
    {
      const float* src = xin + ((size_t)(b * S_ + s0 + sr)) * E_ + h * 64 + sc;
      float4 f0 = *(const float4*)(src);
      float4 f1 = *(const float4*)(src + 4);
      float4 f2 = *(const float4*)(src + 8);
      float4 f3 = *(const float4*)(src + 12);
      float fv[16] = {f0.x, f0.y, f0.z, f0.w, f1.x, f1.y, f1.z, f1.w,
                      f2.x, f2.y, f2.z, f2.w, f3.x, f3.y, f3.z, f3.w};
      bf16x8 hi0, hi1, lo0, lo1;
      #pragma unroll
      for (int j = 0; j < 8; j++) {
        hi0[j] = (__bf16)fv[j];
        lo0[j] = (__bf16)(fv[j] - (float)hi0[j]);
        hi1[j] = (__bf16)fv[8 + j];
        lo1[j] = (__bf16)(fv[8 + j] - (float)hi1[j]);
      }
      SWZ(Xh, scc, sr, p0) = hi0;
      SWZ(Xh, scc, sr, p0 + 1) = hi1;
      SWZ(Xl, scc, sr, p0) = lo0;
      SWZ(Xl, scc, sr, p0 + 1) = lo1;
    }
    __syncthreads();

    bf16x8 ah[2], al[2];
    #pragma unroll
    for (int c = 0; c < 2; c++) {
      ah[c] = SWZ(Xh, c, w * 16 + low, quad);
      al[c] = SWZ(Xl, c, w * 16 + low, quad);
    }

    floatx4 acc[4];
    #pragma unroll
    for (int nn = 0; nn < 4; nn++) {
      floatx4 a = {};
      #pragma unroll
      for (int c = 0; c < 2; c++) {
        const __hip_bfloat16* wp = Wh + (nn * 16 + low) * 64 + c * 32 + quad * 8;
        bf16x8 wh_ = *(const bf16x8*)wp;
        bf16x8 wl_ = *(const bf16x8*)(wp + 4096);
        a = __builtin_amdgcn_mfma_f32_16x16x32_bf16(ah[c], wh_, a, 0, 0, 0);
        a = __builtin_amdgcn_mfma_f32_16x16x32_bf16(al[c], wh_, a, 0, 0, 0);
        a = __builtin_amdgcn_mfma_f32_16x16x32_bf16(ah[c], wl_, a, 0, 0, 0);
      }
      acc[nn] = a;
    }

    if (m < 2) {
      __hip_bfloat16* dh = (m == 0) ? qhi : khi;
      __hip_bfloat16* dl = (m == 0) ? qlo : klo;
      #pragma unroll
      for (int nn = 0; nn < 4; nn++) {
        #pragma unroll
        for (int i = 0; i < 4; i++) {
          const int s = s0 + w * 16 + quad * 4 + i;
          const int d = nn * 16 + low;
          const size_t adr = ((size_t)bh * S_ + s) * 64 + d;
          const float f = acc[nn][i] * sc_m;
          const __hip_bfloat16 hb = __float2bfloat16(f);
          dh[adr] = hb;
          dl[adr] = __float2bfloat16(f - __bfloat162float(hb));
        }
      }
    } else {
      #pragma unroll
      for (int nn = 0; nn < 4; nn++)
        #pragma unroll
        for (int i = 0; i < 4; i++)
          Vt[nn * 16 + low][w * 16 + quad * 4 + i] = (__bf16)acc[nn][i];
      __syncthreads();
      const int dr = t >> 2;
      const int scl = (t & 3) * 16;
      __hip_bfloat16* dst = vt + ((size_t)bh * 64 + dr) * S_ + s0 + scl;
      bf16x8 o0 = *(const bf16x8*)&Vt[dr][scl];
      bf16x8 o1 = *(const bf16x8*)&Vt[dr][scl + 8];
      *(bf16x8*)dst = o0;
      *(bf16x8*)(dst + 8) = o1;
    }
  }
}

// ---------------------------------------------------------------------------
// In-register online softmax (base 2) + pack PV B-fragments.
// ---------------------------------------------------------------------------
__device__ __forceinline__ void softmax_update(
    const floatx4* sa, floatx4* oacc, float& mrow, float& lrow, bf16x8* pb) {
  float rmax;
  {
    float m0 = fmaxf(fmaxf(sa[0][0], sa[0][1]), fmaxf(sa[0][2], sa[0][3]));
    float m1 = fmaxf(fmaxf(sa[1][0], sa[1][1]), fmaxf(sa[1][2], sa[1][3]));
    float m2 = fmaxf(fmaxf(sa[2][0], sa[2][1]), fmaxf(sa[2][2], sa[2][3]));
    float m3 = fmaxf(fmaxf(sa[3][0], sa[3][1]), fmaxf(sa[3][2], sa[3][3]));
    rmax = fmaxf(fmaxf(m0, m1), fmaxf(m2, m3));
    rmax = fmaxf(rmax, __shfl_xor(rmax, 16, 64));
    rmax = fmaxf(rmax, __shfl_xor(rmax, 32, 64));
  }
  if (__any(rmax > mrow)) {           // T13: skip rescale when max static
    const float nm = fmaxf(mrow, rmax);
    const float al = EXP2(mrow - nm);
    mrow = nm;
    lrow *= al;
    #pragma unroll
    for (int dt = 0; dt < 4; dt++) {
      oacc[dt][0] *= al; oacc[dt][1] *= al;
      oacc[dt][2] *= al; oacc[dt][3] *= al;
    }
  }
  float p[4][4];
  float rs;
  {
    float r0_ = 0.f, r1_ = 0.f, r2_ = 0.f, r3_ = 0.f;
    #pragma unroll
    for (int i = 0; i < 4; i++) {
      p[0][i] = EXP2(sa[0][i] - mrow); r0_ += p[0][i];
      p[1][i] = EXP2(sa[1][i] - mrow); r1_ += p[1][i];
      p[2][i] = EXP2(sa[2][i] - mrow); r2_ += p[2][i];
      p[3][i] = EXP2(sa[3][i] - mrow); r3_ += p[3][i];
    }
    rs = (r0_ + r1_) + (r2_ + r3_);
    rs += __shfl_xor(rs, 16, 64);
    rs += __shfl_xor(rs, 32, 64);
  }
  lrow += rs;
  // pb[khalf][j] = P[k = khalf*32 + quad*8 + j][q]
  #pragma unroll
  for (int kh2 = 0; kh2 < 2; kh2++) {
    bf16x8 v;
    v[0] = (__bf16)p[kh2][0]; v[1] = (__bf16)p[kh2][1];
    v[2] = (__bf16)p[kh2][2]; v[3] = (__bf16)p[kh2][3];
    v[4] = (__bf16)p[kh2 + 2][0]; v[5] = (__bf16)p[kh2 + 2][1];
    v[6] = (__bf16)p[kh2 + 2][2]; v[7] = (__bf16)p[kh2 + 2][3];
    pb[kh2] = v;
  }
}

// ---------------------------------------------------------------------------
// MFMA flash attention — R5 structure (best known ~87.5us; converged).
// LDS staging is load-bearing (R6: 358us without it).
// ---------------------------------------------------------------------------
__global__ __launch_bounds__(512, 4) void attn_mfma(
    const __hip_bfloat16* __restrict__ Qhi, const __hip_bfloat16* __restrict__ Qlo,
    const __hip_bfloat16* __restrict__ Khi, const __hip_bfloat16* __restrict__ Klo,
    const __hip_bfloat16* __restrict__ Vtg, __hip_bfloat16* __restrict__ ctx) {
  __shared__ __bf16 Kh[2][2][64][32], Kl[2][2][64][32], Vs[2][2][64][32];
  const int t = threadIdx.x, lane = t & 63, w = t >> 6;   // w: 0..7
  const int quad = lane >> 4, low = lane & 15;
  const int bh = blockIdx.x;                  // bh fastest: q-tiles of one bh
  const int qw = blockIdx.y * 128 + w * 16;   // share an XCD's L2 for K/V

  const int sh = w >> 2;
  const int r0 = (w & 3) * 16;
  const int srow = r0 + (lane >> 2);            // 0..63
  const int sq = (lane & 3) ^ (srow & 3);       // pre-swizzled chunk
  const __hip_bfloat16* gK = Khi + ((size_t)bh * S_ + srow) * 64 + sh * 32 + sq * 8;
  const __hip_bfloat16* gL = Klo + ((size_t)bh * S_ + srow) * 64 + sh * 32 + sq * 8;
  const __hip_bfloat16* gV = Vtg + ((size_t)bh * 64 + srow) * S_ + sh * 32 + sq * 8;

  // Q fragments straight from global (pre-scaled by SCALE2 in qkv_fused)
  bf16x8 qh[2], ql[2];
  {
    const size_t qbase = ((size_t)bh * S_ + qw + low) * 64 + quad * 8;
    qh[0] = *(const bf16x8*)(Qhi + qbase);
    qh[1] = *(const bf16x8*)(Qhi + qbase + 32);
    ql[0] = *(const bf16x8*)(Qlo + qbase);
    ql[1] = *(const bf16x8*)(Qlo + qbase + 32);
  }

  floatx4 oacc[4] = {};
  float mrow = -3e38f, lrow = 0.f;

  // prefetch tile 0 into buf 0
  gload_lds16(gK, (ls_char*)&Kh[0][sh][r0][0]);
  gload_lds16(gL, (ls_char*)&Kl[0][sh][r0][0]);
  gload_lds16(gV, (ls_char*)&Vs[0][sh][r0][0]);

  for (int kt = 0; kt < S_ / 64; kt++) {
    const int cur = kt & 1;
    __syncthreads();   // drains gload_lds (vmcnt) + publishes buf `cur`
    if (kt + 1 < S_ / 64) {
      gload_lds16(gK + (size_t)(kt + 1) * 4096, (ls_char*)&Kh[cur ^ 1][sh][r0][0]);
      gload_lds16(gL + (size_t)(kt + 1) * 4096, (ls_char*)&Kl[cur ^ 1][sh][r0][0]);
      gload_lds16(gV + (size_t)(kt + 1) * 64,   (ls_char*)&Vs[cur ^ 1][sh][r0][0]);
    }

    // QK^T swapped: sa[nn][i] = S[k = (nn&1)*32 + quad*8 + (nn>>1)*4 + i][q]
    floatx4 sa[4];
    __builtin_amdgcn_s_setprio(1);
    #pragma unroll
    for (int nn = 0; nn < 4; nn++) {
      const int prow = (nn & 1) * 32 + (nn >> 1) * 4 + (low >> 2) * 8 + (low & 3);
      bf16x8 kh0 = SWZ(Kh[cur], 0, prow, quad);
      bf16x8 kh1 = SWZ(Kh[cur], 1, prow, quad);
      bf16x8 kl0 = SWZ(Kl[cur], 0, prow, quad);
      bf16x8 kl1 = SWZ(Kl[cur], 1, prow, quad);
      floatx4 s = {};
      s = __builtin_amdgcn_mfma_f32_16x16x32_bf16(kh0, qh[0], s, 0, 0, 0);
      s = __builtin_amdgcn_mfma_f32_16x16x32_bf16(kh1, qh[1], s, 0, 0, 0);
      s = __builtin_amdgcn_mfma_f32_16x16x32_bf16(kl0, qh[0], s, 0, 0, 0);
      s = __builtin_amdgcn_mfma_f32_16x16x32_bf16(kl1, qh[1], s, 0, 0, 0);
      s = __builtin_amdgcn_mfma_f32_16x16x32_bf16(kh0, ql[0], s, 0, 0, 0);
      s = __builtin_amdgcn_mfma_f32_16x16x32_bf16(kh1, ql[1], s, 0, 0, 0);
      sa[nn] = s;
    }
    __builtin_amdgcn_s_setprio(0);

    bf16x8 pb[2];
    softmax_update(sa, oacc, mrow, lrow, pb);

    // PV: oacc[dt] = O^T rows d = dt*16 + quad*4 + i, col q = qw + low
    __builtin_amdgcn_s_setprio(1);
    #pragma unroll
    for (int dt = 0; dt < 4; dt++) {
      bf16x8 vb0 = SWZ(Vs[cur], 0, dt * 16 + low, quad);
      bf16x8 vb1 = SWZ(Vs[cur], 1, dt * 16 + low, quad);
      oacc[dt] = __builtin_amdgcn_mfma_f32_16x16x32_bf16(vb0, pb[0], oacc[dt], 0, 0, 0);
      oacc[dt] = __builtin_amdgcn_mfma_f32_16x16x32_bf16(vb1, pb[1], oacc[dt], 0, 0, 0);
    }
    __builtin_amdgcn_s_setprio(0);
  }

  const float inv = 1.0f / lrow;
  const int b = bh >> 4, h = bh & 15;
  const size_t base = ((size_t)(b * S_ + qw + low)) * E_ + h * 64 + quad * 4;
  #pragma unroll
  for (int dt = 0; dt < 4; dt++) {
    b4s o;
    o.x = __float2bfloat16(oacc[dt][0] * inv);
    o.y = __float2bfloat16(oacc[dt][1] * inv);
    o.z = __float2bfloat16(oacc[dt][2] * inv);
    o.w = __float2bfloat16(oacc[dt][3] * inv);
    *(b4s*)(ctx + base + dt * 16) = o;
  }
}

// ---------------------------------------------------------------------------
// bf16 MFMA GEMM — R8 config restored (best known): BK=64, 2-phase dbuf,
// 64KB LDS. Used for GEMM1 and FF2 (grids don't fit the 256-sq template).
// ---------------------------------------------------------------------------
template <int RELU, int OUT_BF16, int PARTIAL>
__global__ __launch_bounds__(256) void gemm_mfma(
    const __hip_bfloat16* __restrict__ A, const __hip_bfloat16* __restrict__ Wt,
    const float* __restrict__ bias, void* __restrict__ C0, void* __restrict__ C1,
    int M, int N, int Kblk, int lda) {
  __shared__ __bf16 As[2][128][64];
  __shared__ __bf16 Bs[2][128][64];
  const int t = threadIdx.x;
  const int lane = t & 63;
  const int w = t >> 6;
  const int wr = w >> 1, wc = w & 1;
  const int m0 = blockIdx.y * 128, n0 = blockIdx.x * 128;
  void* Cout = (blockIdx.z == 0) ? C0 : C1;

  A += (size_t)blockIdx.z * Kblk;
  Wt += (size_t)blockIdx.z * Kblk;

  floatx4 acc[4][4] = {};
  const int srow = t >> 3;                    // 0..31 (row within 32-row group)
  const int ssc = ((t & 7) ^ (srow & 7)) * 8; // pre-swizzled source col (elems)

  const __hip_bfloat16* gA = A + (size_t)(m0 + srow) * lda + ssc;
  const __hip_bfloat16* gB = Wt + (size_t)(n0 + srow) * lda + ssc;
  const size_t rstep = (size_t)32 * lda;

#define GSTAGE(buf, k0) do {                                      \
    ls_char* lA = (ls_char*)&As[buf][0][0] + w * 1024;            \
    ls_char* lB = (ls_char*)&Bs[buf][0][0] + w * 1024;            \
    gload_lds16(gA + (k0),             lA);                       \
    gload_lds16(gA + (k0) + rstep,     lA + 4096);                \
    gload_lds16(gA + (k0) + 2 * rstep, lA + 8192);                \
    gload_lds16(gA + (k0) + 3 * rstep, lA + 12288);               \
    gload_lds16(gB + (k0),             lB);                       \
    gload_lds16(gB + (k0) + rstep,     lB + 4096);                \
    gload_lds16(gB + (k0) + 2 * rstep, lB + 8192);                \
    gload_lds16(gB + (k0) + 3 * rstep, lB + 12288);               \
  } while (0)

  GSTAGE(0, 0);                    // prologue prefetch
  const int nsteps = Kblk >> 6;
  for (int st = 0; st < nsteps; st++) {
    const int cur = st & 1;
    __syncthreads();               // drains vmcnt for buf `cur`; publishes it
    if (st + 1 < nsteps) GSTAGE(cur ^ 1, (st + 1) * 64);

    #pragma unroll
    for (int ks = 0; ks < 2; ks++) {
      bf16x8 af[4], bfr[4];
      #pragma unroll
      for (int i = 0; i < 4; i++) {
        const int ra = wr * 64 + i * 16 + (lane & 15);
        const int ca = (((lane >> 4) + ks * 4) ^ (ra & 7)) * 8;
        af[i] = *(const bf16x8*)&As[cur][ra][ca];
        const int rb = wc * 64 + i * 16 + (lane & 15);
        const int cb = (((lane >> 4) + ks * 4) ^ (rb & 7)) * 8;
        bfr[i] = *(const bf16x8*)&Bs[cur][rb][cb];
      }
      #pragma unroll
      for (int mi = 0; mi < 4; mi++)
        #pragma unroll
        for (int ni = 0; ni < 4; ni++)
          acc[mi][ni] = __builtin_amdgcn_mfma_f32_16x16x32_bf16(
              af[mi], bfr[ni], acc[mi][ni], 0, 0, 0);
    }
  }
#undef GSTAGE

  const int cil = lane & 15;
  const int quad = lane >> 4;
  #pragma unroll
  for (int ni = 0; ni < 4; ni++) {
    const int col = n0 + wc * 64 + ni * 16 + cil;
    const float bb = PARTIAL ? 0.f : bias[col];
    #pragma unroll
    for (int mi = 0; mi < 4; mi++) {
      const int row = m0 + wr * 64 + mi * 16 + quad * 4;
      #pragma unroll
      for (int i = 0; i < 4; i++) {
        if (PARTIAL) {
          ((float*)Cout)[(size_t)(row + i) * N + col] = acc[mi][ni][i];
        } else {
          float vv = acc[mi][ni][i] + bb;
          if (RELU) vv = fmaxf(vv, 0.f);
          if (OUT_BF16)
            ((__hip_bfloat16*)Cout)[(size_t)(row + i) * N + col] = __float2bfloat16(vv);
          else
            ((float*)Cout)[(size_t)(row + i) * N + col] = vv;
        }
      }
    }
  }
}

// ---------------------------------------------------------------------------
// FF1 GEMM, round 17: 256-sq / 8-wave / 4-phase-per-K-tile (T3 port).
// M=N=4096, K=1024, RELU, bias, bf16 out. Grid 16x16 = 256 blocks = 1/CU,
// 512 threads (2Mx4N waves), per-wave 128x64 output (acc[8][4]), BK=64,
// 128KB dbuf LDS. Phases: quadrants (0,0)->(0,1)->(1,1)->(1,0); B-half-0
// frags kept in registers across the tile. Per phase: ds_read subtile ->
// s_barrier -> setprio(1) -> 16 MFMA -> setprio(0) -> s_barrier. Staging
// (8 gload_lds) issued at phase 1 (all waves provably past the boundary
// barrier, so buf^1 is dead); boundary __syncthreads drains vmcnt with
// ~3 phases of compute already covering the latency.
// ---------------------------------------------------------------------------
__global__ __launch_bounds__(512, 2) void gemm_ff1(
    const __hip_bfloat16* __restrict__ A, const __hip_bfloat16* __restrict__ Wt,
    const float* __restrict__ bias, __hip_bfloat16* __restrict__ C) {
  __shared__ __bf16 As[2][256][64];
  __shared__ __bf16 Bs[2][256][64];
  const int t = threadIdx.x, lane = t & 63, w = t >> 6;    // w: 0..7
  const int quad = lane >> 4, low = lane & 15;
  const int wm = w >> 2, wn = w & 3;                       // 2M x 4N waves
  const int m0 = blockIdx.y * 256, n0 = blockIdx.x * 256;

  floatx4 acc[8][4] = {};

  const int srow = t >> 3;                    // 0..63
  const int ssc = ((t & 7) ^ (srow & 7)) * 8; // pre-swizzled source chunk
  const __hip_bfloat16* gA = A + (size_t)(m0 + srow) * 1024 + ssc;
  const __hip_bfloat16* gB = Wt + (size_t)(n0 + srow) * 1024 + ssc;

#define FSTAGE(buf, k0) do {                                        \
    ls_char* lA = (ls_char*)&As[buf][0][0] + w * 1024;              \
    ls_char* lB = (ls_char*)&Bs[buf][0][0] + w * 1024;              \
    gload_lds16(gA + (k0),          lA);                            \
    gload_lds16(gA + (k0) + 65536,  lA + 8192);                     \
    gload_lds16(gA + (k0) + 131072, lA + 16384);                    \
    gload_lds16(gA + (k0) + 196608, lA + 24576);                    \
    gload_lds16(gB + (k0),          lB);                            \
    gload_lds16(gB + (k0) + 65536,  lB + 8192);                     \
    gload_lds16(gB + (k0) + 131072, lB + 16384);                    \
    gload_lds16(gB + (k0) + 196608, lB + 24576);                    \
  } while (0)

#define LDA_HALF(mh) do {                                                     \
    _Pragma("unroll")                                                         \
    for (int mi = 0; mi < 4; mi++) {                                          \
      const int ra = wm * 128 + (mh) * 64 + mi * 16 + low;                    \
      af[mi][0] = *(const bf16x8*)&As[cur][ra][((quad) ^ (ra & 7)) * 8];      \
      af[mi][1] = *(const bf16x8*)&As[cur][ra][((4 + quad) ^ (ra & 7)) * 8];  \
    }                                                                         \
  } while (0)

#define LDB_HALF(dst, nh) do {                                                \
    _Pragma("unroll")                                                         \
    for (int ni = 0; ni < 2; ni++) {                                          \
      const int rb = wn * 64 + (nh) * 32 + ni * 16 + low;                     \
      dst[ni][0] = *(const bf16x8*)&Bs[cur][rb][((quad) ^ (rb & 7)) * 8];     \
      dst[ni][1] = *(const bf16x8*)&Bs[cur][rb][((4 + quad) ^ (rb & 7)) * 8]; \
    }                                                                         \
  } while (0)

#define MFMA_Q(bfr, mh, nh) do {                                              \
    __builtin_amdgcn_s_setprio(1);                                            \
    _Pragma("unroll")                                                         \
    for (int mi = 0; mi < 4; mi++)                                            \
      _Pragma("unroll")                                                       \
      for (int ni = 0; ni < 2; ni++) {                                        \
        acc[(mh)*4+mi][(nh)*2+ni] = __builtin_amdgcn_mfma_f32_16x16x32_bf16(  \
            af[mi][0], bfr[ni][0], acc[(mh)*4+mi][(nh)*2+ni], 0, 0, 0);       \
        acc[(mh)*4+mi][(nh)*2+ni] = __builtin_amdgcn_mfma_f32_16x16x32_bf16(  \
            af[mi][1], bfr[ni][1], acc[(mh)*4+mi][(nh)*2+ni], 0, 0, 0);       \
      }                                                                       \
    __builtin_amdgcn_s_setprio(0);                                            \
  } while (0)

  FSTAGE(0, 0);
  bf16x8 af[4][2], bA[2][2], bB[2][2];

  for (int kt = 0; kt < 16; kt++) {
    const int cur = kt & 1;
    __syncthreads();             // drain DMA (vmcnt0) + publish buf `cur`

    // P0: quadrant (0,0)
    LDA_HALF(0);
    LDB_HALF(bA, 0);
    sbar();
    MFMA_Q(bA, 0, 0);
    sbar();

    // P1: quadrant (0,1); stage next K-tile (buf^1 is dead now)
    LDB_HALF(bB, 1);
    if (kt + 1 < 16) FSTAGE(cur ^ 1, (kt + 1) * 64);
    sbar();
    MFMA_Q(bB, 0, 1);
    sbar();

    // P2: quadrant (1,1)
    LDA_HALF(1);
    sbar();
    MFMA_Q(bB, 1, 1);
    sbar();

    // P3: quadrant (1,0) — bA reused from registers
    MFMA_Q(bA, 1, 0);
  }
#undef FSTAGE
#undef LDA_HALF
#undef LDB_HALF
#undef MFMA_Q

  #pragma unroll
  for (int ni = 0; ni < 4; ni++) {
    const int col = n0 + wn * 64 + ni * 16 + low;
    const float bb = bias[col];
    #pragma unroll
    for (int mi = 0; mi < 8; mi++) {
      const int row = m0 + wm * 128 + mi * 16 + quad * 4;
      #pragma unroll
      for (int i = 0; i < 4; i++) {
        float vv = fmaxf(acc[mi][ni][i] + bb, 0.f);
        C[(size_t)(row + i) * 4096 + col] = __float2bfloat16(vv);
      }
    }
  }
}

// ---------------------------------------------------------------------------
// out = LayerNorm(a0 [+ a1] [+ bias] + r)*g + b ; optional secondary bf16 out.
// ---------------------------------------------------------------------------
template <int EMIT_BF16, int HAS_A1, int HAS_BIAS>
__global__ __launch_bounds__(256) void add_ln(
    const float* __restrict__ a0, const float* __restrict__ a1,
    const float* __restrict__ r, const float* __restrict__ bias,
    const float* __restrict__ g, const float* __restrict__ bt,
    float* __restrict__ out, __hip_bfloat16* __restrict__ outb) {
  __shared__ float red[16];
  const int tok = blockIdx.x, t = threadIdx.x;
  float4 av = ((const float4*)(a0 + (size_t)tok * E_))[t];
  float4 rv = ((const float4*)(r + (size_t)tok * E_))[t];
  float4 x;
  x.x = av.x + rv.x; x.y = av.y + rv.y; x.z = av.z + rv.z; x.w = av.w + rv.w;
  if (HAS_A1) {
    float4 a2 = ((const float4*)(a1 + (size_t)tok * E_))[t];
    x.x += a2.x; x.y += a2.y; x.z += a2.z; x.w += a2.w;
  }
  if (HAS_BIAS) {
    float4 cv = ((const float4*)bias)[t];
    x.x += cv.x; x.y += cv.y; x.z += cv.z; x.w += cv.w;
  }
  float sum = x.x + x.y + x.z + x.w;
  float ssq = x.x * x.x + x.y * x.y + x.z * x.z + x.w * x.w;
  #pragma unroll
  for (int off = 32; off >= 1; off >>= 1) {
    sum += __shfl_down(sum, off, 64);
    ssq += __shfl_down(ssq, off, 64);
  }
  const int wave = t >> 6;
  if ((t & 63) == 0) { red[wave] = sum; red[4 + wave] = ssq; }
  __syncthreads();
  if (t == 0) {
    float s = red[0] + red[1] + red[2] + red[3];
    float qq = red[4] + red[5] + red[6] + red[7];
    float mu = s * (1.0f / E_);
    red[8] = mu;
    red[9] = qq * (1.0f / E_) - mu * mu;
  }
  __syncthreads();
  const float mu = red[8];
  const float inv = rsqrtf(red[9] + 1e-5f);
  float4 gv = ((const float4*)g)[t];
  float4 bv = ((const float4*)bt)[t];
  float4 o;
  o.x = (x.x - mu) * inv * gv.x + bv.x;
  o.y = (x.y - mu) * inv * gv.y + bv.y;
  o.z = (x.z - mu) * inv * gv.z + bv.z;
  o.w = (x.w - mu) * inv * gv.w + bv.w;
  ((float4*)(out + (size_t)tok * E_))[t] = o;
  if (EMIT_BF16) {
    b4s ob;
    ob.x = __float2bfloat16(o.x); ob.y = __float2bfloat16(o.y);
    ob.z = __float2bfloat16(o.z); ob.w = __float2bfloat16(o.w);
    *(b4s*)(outb + (size_t)tok * E_ + t * 4) = ob;
  }
}

// ---------------------------------------------------------------------------
extern "C" void kernel_launch(void* const* d_in, const int* in_sizes, int n_in,
                              void* d_out, int out_size, void* d_ws, size_t ws_size,
                              hipStream_t stream) {
  const float* queries = (const float*)d_in[0];
  const float* keys    = (const float*)d_in[1];
  const float* values  = (const float*)d_in[2];
  const float* Wq  = (const float*)d_in[4];
  const float* Wk  = (const float*)d_in[5];
  const float* Wv  = (const float*)d_in[6];
  const float* Wfc = (const float*)d_in[7];
  const float* bfc = (const float*)d_in[8];
  const float* W1  = (const float*)d_in[9];
  const float* b1  = (const float*)d_in[10];
  const float* W2  = (const float*)d_in[11];
  const float* b2  = (const float*)d_in[12];
  const float* ln1_g = (const float*)d_in[13];
  const float* ln1_b = (const float*)d_in[14];
  const float* ln2_g = (const float*)d_in[15];
  const float* ln2_b = (const float*)d_in[16];

  const size_t M1 = 1048576;
  float* ws = (float*)d_ws;
  float* P0  = ws;             // 4M fl: split-K partial 0
  float* P1  = ws + 4 * M1;    // 4M fl: split-K partial 1
  float* Hf  = ws + 8 * M1;    // 4M fl
  __hip_bfloat16* bb = (__hip_bfloat16*)(ws + 12 * M1);
  __hip_bfloat16* CTXb = bb;                  //  4M
  __hip_bfloat16* Hb   = bb + 4 * M1;         //  4M
  __hip_bfloat16* Wfcb = bb + 8 * M1;         //  1M
  __hip_bfloat16* W1b  = bb + 9 * M1;         //  4M
  __hip_bfloat16* W2b  = bb + 13 * M1;        //  4M
  // attention temps (17M..37M) alias FF1b (17M..33M): FF1b written after attn
  __hip_bfloat16* Qhi  = bb + 17 * M1;        //  4M
  __hip_bfloat16* Qlo  = bb + 21 * M1;        //  4M
  __hip_bfloat16* Khi  = bb + 25 * M1;        //  4M
  __hip_bfloat16* Klo  = bb + 29 * M1;        //  4M
  __hip_bfloat16* Vtb  = bb + 33 * M1;        //  4M
  __hip_bfloat16* FF1b = bb + 17 * M1;        // 16M (after attention)
  __hip_bfloat16* Whlb = bb + 37 * M1;        // 24K
  float* out = (float*)d_out;

  cast_all<<<9228, 256, 0, stream>>>(Wfc, W1, W2, Wfcb, W1b, W2b,
                                     Wq, Wk, Wv, Whlb);

  qkv_fused<<<dim3(S_ / 64, B_ * H_), 256, 0, stream>>>(
      queries, keys, values, Whlb, Qhi, Qlo, Khi, Klo, Vtb);
  attn_mfma<<<dim3(B_ * H_, S_ / 128), 512, 0, stream>>>(
      Qhi, Qlo, Khi, Klo, Vtb, CTXb);
  gemm_mfma<0, 0, 1><<<dim3(E_ / 128, TOK / 128, 2), 256, 0, stream>>>(
      CTXb, Wfcb, nullptr, P0, P1, TOK, E_, 512, E_);
  add_ln<1, 1, 1><<<TOK, 256, 0, stream>>>(
      P0, P1, queries, bfc, ln1_g, ln1_b, Hf, Hb);
  gemm_ff1<<<dim3(4 * E_ / 256, TOK / 256), 512, 0, stream>>>(
      Hb, W1b, b1, FF1b);
  gemm_mfma<0, 0, 1><<<dim3(E_ / 128, TOK / 128, 2), 256, 0, stream>>>(
      FF1b, W2b, nullptr, P0, P1, TOK, E_, 2048, 4 * E_);
  add_ln<0, 1, 1><<<TOK, 256, 0, stream>>>(
      P0, P1, Hf, b2, ln2_g, ln2_b, out, nullptr);
}

// Round 11
// 377.183 us; speedup vs baseline: 1.0599x; 1.0314x over previous
//
#include <hip/hip_runtime.h>
#include <hip/hip_bf16.h>
#include <math.h>

#define B_ 2
#define S_ 2048
#define E_ 1024
#define H_ 16
#define D_ 64
#define TOK (B_*S_)          // 4096 tokens
// Q pre-scale folds sqrt(S) (reference quirk) and log2(e) so attn uses raw
// v_exp_f32 (base-2): softmax_2(x*log2e) == softmax_e(x), exactly.
#define SCALE2 (45.254833995939045f * 1.44269504088896340f)

typedef __bf16 bf16x8 __attribute__((ext_vector_type(8)));
typedef float floatx4 __attribute__((ext_vector_type(4)));
struct b4s { __hip_bfloat16 x, y, z, w; };   // 8-byte packed bf16 quad

typedef const __attribute__((address_space(1))) char ga_char;
typedef __attribute__((address_space(3))) char ls_char;

// async 16B/lane global->LDS copy; lds dest = wave-uniform base + lane*16
__device__ __forceinline__ void gload_lds16(const void* g, ls_char* l) {
  __builtin_amdgcn_global_load_lds((ga_char*)g, l, 16, 0, 0);
}

#if __has_builtin(__builtin_amdgcn_exp2f)
#define EXP2(x) __builtin_amdgcn_exp2f(x)
#else
#define EXP2(x) exp2f(x)
#endif

// XOR chunk swizzle for [64][32]-bf16 half-tiles
#define SWZ(arr, half, row, qpos) \
  (*(bf16x8*)&arr[half][row][(((qpos) ^ ((row) & 3)) * 8)])

// raw workgroup barrier, fenced so memory ops can't cross it
__device__ __forceinline__ void sbar() {
  asm volatile("" ::: "memory");
  __builtin_amdgcn_s_barrier();
  asm volatile("" ::: "memory");
}
// counted vmcnt wait (T4): never drain to 0 in the steady-state loop
#define VMW(n) asm volatile("s_waitcnt vmcnt(" #n ")" ::: "memory")

// ---------------------------------------------------------------------------
// All weight casts in ONE kernel.
// ---------------------------------------------------------------------------
__global__ __launch_bounds__(256) void cast_all(
    const float* __restrict__ Wfc, const float* __restrict__ W1,
    const float* __restrict__ W2, __hip_bfloat16* __restrict__ Wfcb,
    __hip_bfloat16* __restrict__ W1b, __hip_bfloat16* __restrict__ W2b,
    const float* __restrict__ Wq, const float* __restrict__ Wk,
    const float* __restrict__ Wv, __hip_bfloat16* __restrict__ Whl) {
  const int i = blockIdx.x * 256 + threadIdx.x;
  if (i < 2359296) {
    const float* src; __hip_bfloat16* dst; int j;
    if (i < 262144)       { src = Wfc; dst = Wfcb; j = i; }
    else if (i < 1310720) { src = W1;  dst = W1b;  j = i - 262144; }
    else                  { src = W2;  dst = W2b;  j = i - 1310720; }
    float4 v = ((const float4*)src)[j];
    b4s o;
    o.x = __float2bfloat16(v.x); o.y = __float2bfloat16(v.y);
    o.z = __float2bfloat16(v.z); o.w = __float2bfloat16(v.w);
    *(b4s*)(dst + (size_t)j * 4) = o;
  } else if (i < 2362368) {
    const int idx = i - 2359296;
    const int m = idx >> 10;
    const int off = (idx & 1023) * 4;
    const float* W = (m == 0) ? Wq : (m == 1) ? Wk : Wv;
    float4 v = *(const float4*)(W + off);
    b4s hi, lo;
    hi.x = __float2bfloat16(v.x); lo.x = __float2bfloat16(v.x - __bfloat162float(hi.x));
    hi.y = __float2bfloat16(v.y); lo.y = __float2bfloat16(v.y - __bfloat162float(hi.y));
    hi.z = __float2bfloat16(v.z); lo.z = __float2bfloat16(v.z - __bfloat162float(hi.z));
    hi.w = __float2bfloat16(v.w); lo.w = __float2bfloat16(v.w - __bfloat162float(hi.w));
    *(b4s*)(Whl + (size_t)m * 8192 + off) = hi;
    *(b4s*)(Whl + (size_t)m * 8192 + 4096 + off) = lo;
  }
}

// ---------------------------------------------------------------------------
// Fused QKV projection + hi/lo split + V transpose.
// Q output pre-scaled by SCALE2 = sqrt(S)*log2e.
// ---------------------------------------------------------------------------
__global__ __launch_bounds__(256) void qkv_fused(
    const float* __restrict__ xq, const float* __restrict__ xk,
    const float* __restrict__ xv, const __hip_bfloat16* __restrict__ Whl,
    __hip_bfloat16* __restrict__ qhi, __hip_bfloat16* __restrict__ qlo,
    __hip_bfloat16* __restrict__ khi, __hip_bfloat16* __restrict__ klo,
    __hip_bfloat16* __restrict__ vt) {
  __shared__ __bf16 Xh[2][64][32], Xl[2][64][32];
  __shared__ __bf16 Vt[64][72];
  const int t = threadIdx.x, lane = t & 63, w = t >> 6;
  const int quad = lane >> 4, low = lane & 15;
  const int bh = blockIdx.y;
  const int b = bh >> 4, h = bh & 15;
  const int s0 = blockIdx.x * 64;
  const int sr = t >> 2;
  const int sc = (t & 3) * 16;
  const int scc = sc >> 5;
  const int p0 = (sc & 31) >> 3;   // logical 16B chunk within half: 0 or 2

  for (int m = 0; m < 3; m++) {
    const float* xin = (m == 0) ? xq : (m == 1) ? xk : xv;
    const __hip_bfloat16* Wh = Whl + (size_t)m * 8192;
    const float sc_m = (m == 0) ? SCALE2 : 1.0f;

    __syncthreads();
    {
      const float* src = xin + ((size_t)(b * S_ + s0 + sr)) * E_ + h * 64 + sc;
      float4 f0 = *(const float4*)(src);
      float4 f1 = *(const float4*)(src + 4);
      float4 f2 = *(const float4*)(src + 8);
      float4 f3 = *(const float4*)(src + 12);
      float fv[16] = {f0.x, f0.y, f0.z, f0.w, f1.x, f1.y, f1.z, f1.w,
                      f2.x, f2.y, f2.z, f2.w, f3.x, f3.y, f3.z, f3.w};
      bf16x8 hi0, hi1, lo0, lo1;
      #pragma unroll
      for (int j = 0; j < 8; j++) {
        hi0[j] = (__bf16)fv[j];
        lo0[j] = (__bf16)(fv[j] - (float)hi0[j]);
        hi1[j] = (__bf16)fv[8 + j];
        lo1[j] = (__bf16)(fv[8 + j] - (float)hi1[j]);
      }
      SWZ(Xh, scc, sr, p0) = hi0;
      SWZ(Xh, scc, sr, p0 + 1) = hi1;
      SWZ(Xl, scc, sr, p0) = lo0;
      SWZ(Xl, scc, sr, p0 + 1) = lo1;
    }
    __syncthreads();

    bf16x8 ah[2], al[2];
    #pragma unroll
    for (int c = 0; c < 2; c++) {
      ah[c] = SWZ(Xh, c, w * 16 + low, quad);
      al[c] = SWZ(Xl, c, w * 16 + low, quad);
    }

    floatx4 acc[4];
    #pragma unroll
    for (int nn = 0; nn < 4; nn++) {
      floatx4 a = {};
      #pragma unroll
      for (int c = 0; c < 2; c++) {
        const __hip_bfloat16* wp = Wh + (nn * 16 + low) * 64 + c * 32 + quad * 8;
        bf16x8 wh_ = *(const bf16x8*)wp;
        bf16x8 wl_ = *(const bf16x8*)(wp + 4096);
        a = __builtin_amdgcn_mfma_f32_16x16x32_bf16(ah[c], wh_, a, 0, 0, 0);
        a = __builtin_amdgcn_mfma_f32_16x16x32_bf16(al[c], wh_, a, 0, 0, 0);
        a = __builtin_amdgcn_mfma_f32_16x16x32_bf16(ah[c], wl_, a, 0, 0, 0);
      }
      acc[nn] = a;
    }

    if (m < 2) {
      __hip_bfloat16* dh = (m == 0) ? qhi : khi;
      __hip_bfloat16* dl = (m == 0) ? qlo : klo;
      #pragma unroll
      for (int nn = 0; nn < 4; nn++) {
        #pragma unroll
        for (int i = 0; i < 4; i++) {
          const int s = s0 + w * 16 + quad * 4 + i;
          const int d = nn * 16 + low;
          const size_t adr = ((size_t)bh * S_ + s) * 64 + d;
          const float f = acc[nn][i] * sc_m;
          const __hip_bfloat16 hb = __float2bfloat16(f);
          dh[adr] = hb;
          dl[adr] = __float2bfloat16(f - __bfloat162float(hb));
        }
      }
    } else {
      #pragma unroll
      for (int nn = 0; nn < 4; nn++)
        #pragma unroll
        for (int i = 0; i < 4; i++)
          Vt[nn * 16 + low][w * 16 + quad * 4 + i] = (__bf16)acc[nn][i];
      __syncthreads();
      const int dr = t >> 2;
      const int scl = (t & 3) * 16;
      __hip_bfloat16* dst = vt + ((size_t)bh * 64 + dr) * S_ + s0 + scl;
      bf16x8 o0 = *(const bf16x8*)&Vt[dr][scl];
      bf16x8 o1 = *(const bf16x8*)&Vt[dr][scl + 8];
      *(bf16x8*)dst = o0;
      *(bf16x8*)(dst + 8) = o1;
    }
  }
}

// ---------------------------------------------------------------------------
// In-register online softmax (base 2) + pack PV B-fragments.
// ---------------------------------------------------------------------------
__device__ __forceinline__ void softmax_update(
    const floatx4* sa, floatx4* oacc, float& mrow, float& lrow, bf16x8* pb) {
  float rmax;
  {
    float m0 = fmaxf(fmaxf(sa[0][0], sa[0][1]), fmaxf(sa[0][2], sa[0][3]));
    float m1 = fmaxf(fmaxf(sa[1][0], sa[1][1]), fmaxf(sa[1][2], sa[1][3]));
    float m2 = fmaxf(fmaxf(sa[2][0], sa[2][1]), fmaxf(sa[2][2], sa[2][3]));
    float m3 = fmaxf(fmaxf(sa[3][0], sa[3][1]), fmaxf(sa[3][2], sa[3][3]));
    rmax = fmaxf(fmaxf(m0, m1), fmaxf(m2, m3));
    rmax = fmaxf(rmax, __shfl_xor(rmax, 16, 64));
    rmax = fmaxf(rmax, __shfl_xor(rmax, 32, 64));
  }
  if (__any(rmax > mrow)) {           // T13: skip rescale when max static
    const float nm = fmaxf(mrow, rmax);
    const float al = EXP2(mrow - nm);
    mrow = nm;
    lrow *= al;
    #pragma unroll
    for (int dt = 0; dt < 4; dt++) {
      oacc[dt][0] *= al; oacc[dt][1] *= al;
      oacc[dt][2] *= al; oacc[dt][3] *= al;
    }
  }
  float p[4][4];
  float rs;
  {
    float r0_ = 0.f, r1_ = 0.f, r2_ = 0.f, r3_ = 0.f;
    #pragma unroll
    for (int i = 0; i < 4; i++) {
      p[0][i] = EXP2(sa[0][i] - mrow); r0_ += p[0][i];
      p[1][i] = EXP2(sa[1][i] - mrow); r1_ += p[1][i];
      p[2][i] = EXP2(sa[2][i] - mrow); r2_ += p[2][i];
      p[3][i] = EXP2(sa[3][i] - mrow); r3_ += p[3][i];
    }
    rs = (r0_ + r1_) + (r2_ + r3_);
    rs += __shfl_xor(rs, 16, 64);
    rs += __shfl_xor(rs, 32, 64);
  }
  lrow += rs;
  // pb[khalf][j] = P[k = khalf*32 + quad*8 + j][q]
  #pragma unroll
  for (int kh2 = 0; kh2 < 2; kh2++) {
    bf16x8 v;
    v[0] = (__bf16)p[kh2][0]; v[1] = (__bf16)p[kh2][1];
    v[2] = (__bf16)p[kh2][2]; v[3] = (__bf16)p[kh2][3];
    v[4] = (__bf16)p[kh2 + 2][0]; v[5] = (__bf16)p[kh2 + 2][1];
    v[6] = (__bf16)p[kh2 + 2][2]; v[7] = (__bf16)p[kh2 + 2][3];
    pb[kh2] = v;
  }
}

// ---------------------------------------------------------------------------
// MFMA flash attention — R5 structure (best known ~87.5us; converged).
// LDS staging is load-bearing (R6: 358us without it).
// ---------------------------------------------------------------------------
__global__ __launch_bounds__(512, 4) void attn_mfma(
    const __hip_bfloat16* __restrict__ Qhi, const __hip_bfloat16* __restrict__ Qlo,
    const __hip_bfloat16* __restrict__ Khi, const __hip_bfloat16* __restrict__ Klo,
    const __hip_bfloat16* __restrict__ Vtg, __hip_bfloat16* __restrict__ ctx) {
  __shared__ __bf16 Kh[2][2][64][32], Kl[2][2][64][32], Vs[2][2][64][32];
  const int t = threadIdx.x, lane = t & 63, w = t >> 6;   // w: 0..7
  const int quad = lane >> 4, low = lane & 15;
  const int bh = blockIdx.x;                  // bh fastest: q-tiles of one bh
  const int qw = blockIdx.y * 128 + w * 16;   // share an XCD's L2 for K/V

  const int sh = w >> 2;
  const int r0 = (w & 3) * 16;
  const int srow = r0 + (lane >> 2);            // 0..63
  const int sq = (lane & 3) ^ (srow & 3);       // pre-swizzled chunk
  const __hip_bfloat16* gK = Khi + ((size_t)bh * S_ + srow) * 64 + sh * 32 + sq * 8;
  const __hip_bfloat16* gL = Klo + ((size_t)bh * S_ + srow) * 64 + sh * 32 + sq * 8;
  const __hip_bfloat16* gV = Vtg + ((size_t)bh * 64 + srow) * S_ + sh * 32 + sq * 8;

  // Q fragments straight from global (pre-scaled by SCALE2 in qkv_fused)
  bf16x8 qh[2], ql[2];
  {
    const size_t qbase = ((size_t)bh * S_ + qw + low) * 64 + quad * 8;
    qh[0] = *(const bf16x8*)(Qhi + qbase);
    qh[1] = *(const bf16x8*)(Qhi + qbase + 32);
    ql[0] = *(const bf16x8*)(Qlo + qbase);
    ql[1] = *(const bf16x8*)(Qlo + qbase + 32);
  }

  floatx4 oacc[4] = {};
  float mrow = -3e38f, lrow = 0.f;

  // prefetch tile 0 into buf 0
  gload_lds16(gK, (ls_char*)&Kh[0][sh][r0][0]);
  gload_lds16(gL, (ls_char*)&Kl[0][sh][r0][0]);
  gload_lds16(gV, (ls_char*)&Vs[0][sh][r0][0]);

  for (int kt = 0; kt < S_ / 64; kt++) {
    const int cur = kt & 1;
    __syncthreads();   // drains gload_lds (vmcnt) + publishes buf `cur`
    if (kt + 1 < S_ / 64) {
      gload_lds16(gK + (size_t)(kt + 1) * 4096, (ls_char*)&Kh[cur ^ 1][sh][r0][0]);
      gload_lds16(gL + (size_t)(kt + 1) * 4096, (ls_char*)&Kl[cur ^ 1][sh][r0][0]);
      gload_lds16(gV + (size_t)(kt + 1) * 64,   (ls_char*)&Vs[cur ^ 1][sh][r0][0]);
    }

    // QK^T swapped: sa[nn][i] = S[k = (nn&1)*32 + quad*8 + (nn>>1)*4 + i][q]
    floatx4 sa[4];
    __builtin_amdgcn_s_setprio(1);
    #pragma unroll
    for (int nn = 0; nn < 4; nn++) {
      const int prow = (nn & 1) * 32 + (nn >> 1) * 4 + (low >> 2) * 8 + (low & 3);
      bf16x8 kh0 = SWZ(Kh[cur], 0, prow, quad);
      bf16x8 kh1 = SWZ(Kh[cur], 1, prow, quad);
      bf16x8 kl0 = SWZ(Kl[cur], 0, prow, quad);
      bf16x8 kl1 = SWZ(Kl[cur], 1, prow, quad);
      floatx4 s = {};
      s = __builtin_amdgcn_mfma_f32_16x16x32_bf16(kh0, qh[0], s, 0, 0, 0);
      s = __builtin_amdgcn_mfma_f32_16x16x32_bf16(kh1, qh[1], s, 0, 0, 0);
      s = __builtin_amdgcn_mfma_f32_16x16x32_bf16(kl0, qh[0], s, 0, 0, 0);
      s = __builtin_amdgcn_mfma_f32_16x16x32_bf16(kl1, qh[1], s, 0, 0, 0);
      s = __builtin_amdgcn_mfma_f32_16x16x32_bf16(kh0, ql[0], s, 0, 0, 0);
      s = __builtin_amdgcn_mfma_f32_16x16x32_bf16(kh1, ql[1], s, 0, 0, 0);
      sa[nn] = s;
    }
    __builtin_amdgcn_s_setprio(0);

    bf16x8 pb[2];
    softmax_update(sa, oacc, mrow, lrow, pb);

    // PV: oacc[dt] = O^T rows d = dt*16 + quad*4 + i, col q = qw + low
    __builtin_amdgcn_s_setprio(1);
    #pragma unroll
    for (int dt = 0; dt < 4; dt++) {
      bf16x8 vb0 = SWZ(Vs[cur], 0, dt * 16 + low, quad);
      bf16x8 vb1 = SWZ(Vs[cur], 1, dt * 16 + low, quad);
      oacc[dt] = __builtin_amdgcn_mfma_f32_16x16x32_bf16(vb0, pb[0], oacc[dt], 0, 0, 0);
      oacc[dt] = __builtin_amdgcn_mfma_f32_16x16x32_bf16(vb1, pb[1], oacc[dt], 0, 0, 0);
    }
    __builtin_amdgcn_s_setprio(0);
  }

  const float inv = 1.0f / lrow;
  const int b = bh >> 4, h = bh & 15;
  const size_t base = ((size_t)(b * S_ + qw + low)) * E_ + h * 64 + quad * 4;
  #pragma unroll
  for (int dt = 0; dt < 4; dt++) {
    b4s o;
    o.x = __float2bfloat16(oacc[dt][0] * inv);
    o.y = __float2bfloat16(oacc[dt][1] * inv);
    o.z = __float2bfloat16(oacc[dt][2] * inv);
    o.w = __float2bfloat16(oacc[dt][3] * inv);
    *(b4s*)(ctx + base + dt * 16) = o;
  }
}

// ---------------------------------------------------------------------------
// bf16 MFMA GEMM — R8 config (best known): BK=64, 2-phase dbuf, 64KB LDS.
// Used for GEMM1 and FF2.
// ---------------------------------------------------------------------------
template <int RELU, int OUT_BF16, int PARTIAL>
__global__ __launch_bounds__(256) void gemm_mfma(
    const __hip_bfloat16* __restrict__ A, const __hip_bfloat16* __restrict__ Wt,
    const float* __restrict__ bias, void* __restrict__ C0, void* __restrict__ C1,
    int M, int N, int Kblk, int lda) {
  __shared__ __bf16 As[2][128][64];
  __shared__ __bf16 Bs[2][128][64];
  const int t = threadIdx.x;
  const int lane = t & 63;
  const int w = t >> 6;
  const int wr = w >> 1, wc = w & 1;
  const int m0 = blockIdx.y * 128, n0 = blockIdx.x * 128;
  void* Cout = (blockIdx.z == 0) ? C0 : C1;

  A += (size_t)blockIdx.z * Kblk;
  Wt += (size_t)blockIdx.z * Kblk;

  floatx4 acc[4][4] = {};
  const int srow = t >> 3;                    // 0..31 (row within 32-row group)
  const int ssc = ((t & 7) ^ (srow & 7)) * 8; // pre-swizzled source col (elems)

  const __hip_bfloat16* gA = A + (size_t)(m0 + srow) * lda + ssc;
  const __hip_bfloat16* gB = Wt + (size_t)(n0 + srow) * lda + ssc;
  const size_t rstep = (size_t)32 * lda;

#define GSTAGE(buf, k0) do {                                      \
    ls_char* lA = (ls_char*)&As[buf][0][0] + w * 1024;            \
    ls_char* lB = (ls_char*)&Bs[buf][0][0] + w * 1024;            \
    gload_lds16(gA + (k0),             lA);                       \
    gload_lds16(gA + (k0) + rstep,     lA + 4096);                \
    gload_lds16(gA + (k0) + 2 * rstep, lA + 8192);                \
    gload_lds16(gA + (k0) + 3 * rstep, lA + 12288);               \
    gload_lds16(gB + (k0),             lB);                       \
    gload_lds16(gB + (k0) + rstep,     lB + 4096);                \
    gload_lds16(gB + (k0) + 2 * rstep, lB + 8192);                \
    gload_lds16(gB + (k0) + 3 * rstep, lB + 12288);               \
  } while (0)

  GSTAGE(0, 0);                    // prologue prefetch
  const int nsteps = Kblk >> 6;
  for (int st = 0; st < nsteps; st++) {
    const int cur = st & 1;
    __syncthreads();               // drains vmcnt for buf `cur`; publishes it
    if (st + 1 < nsteps) GSTAGE(cur ^ 1, (st + 1) * 64);

    #pragma unroll
    for (int ks = 0; ks < 2; ks++) {
      bf16x8 af[4], bfr[4];
      #pragma unroll
      for (int i = 0; i < 4; i++) {
        const int ra = wr * 64 + i * 16 + (lane & 15);
        const int ca = (((lane >> 4) + ks * 4) ^ (ra & 7)) * 8;
        af[i] = *(const bf16x8*)&As[cur][ra][ca];
        const int rb = wc * 64 + i * 16 + (lane & 15);
        const int cb = (((lane >> 4) + ks * 4) ^ (rb & 7)) * 8;
        bfr[i] = *(const bf16x8*)&Bs[cur][rb][cb];
      }
      #pragma unroll
      for (int mi = 0; mi < 4; mi++)
        #pragma unroll
        for (int ni = 0; ni < 4; ni++)
          acc[mi][ni] = __builtin_amdgcn_mfma_f32_16x16x32_bf16(
              af[mi], bfr[ni], acc[mi][ni], 0, 0, 0);
    }
  }
#undef GSTAGE

  const int cil = lane & 15;
  const int quad = lane >> 4;
  #pragma unroll
  for (int ni = 0; ni < 4; ni++) {
    const int col = n0 + wc * 64 + ni * 16 + cil;
    const float bb = PARTIAL ? 0.f : bias[col];
    #pragma unroll
    for (int mi = 0; mi < 4; mi++) {
      const int row = m0 + wr * 64 + mi * 16 + quad * 4;
      #pragma unroll
      for (int i = 0; i < 4; i++) {
        if (PARTIAL) {
          ((float*)Cout)[(size_t)(row + i) * N + col] = acc[mi][ni][i];
        } else {
          float vv = acc[mi][ni][i] + bb;
          if (RELU) vv = fmaxf(vv, 0.f);
          if (OUT_BF16)
            ((__hip_bfloat16*)Cout)[(size_t)(row + i) * N + col] = __float2bfloat16(vv);
          else
            ((float*)Cout)[(size_t)(row + i) * N + col] = vv;
        }
      }
    }
  }
}

// ---------------------------------------------------------------------------
// FF1 GEMM, round 18: 256-sq / 8-wave / 4-phase + COUNTED vmcnt (T4 — the
// piece R10 was missing; m218: drain0 8-phase == 1-phase, counted = +38-73%).
// K-tile staged as 4 half-tiles (A0,B0,B1,A1; 2 gload_lds each), one per
// phase of the PREVIOUS tile, issue order == next tile's consumption order:
//   P0 reads A0+B0, P1 reads B1, P2 reads A1, P3 register-carried.
// Per phase: vmcnt(4) (allows 2 newest halves in flight; per-wave counts
// made collective by the following s_barrier) -> ds_read frags -> issue one
// half-stage -> 16 MFMA. Last tile: vmcnt(2)/vmcnt(0) at P1/P2 (no trailing
// stages pad the FIFO). Every half gets 3-4 phases (~1500cy) to land.
// B rows remapped rb = nh*128 + wn*32 + ni*16 + low so each phase's
// collective B reads align with contiguous staged halves.
// ---------------------------------------------------------------------------
__global__ __launch_bounds__(512, 2) void gemm_ff1(
    const __hip_bfloat16* __restrict__ A, const __hip_bfloat16* __restrict__ Wt,
    const float* __restrict__ bias, __hip_bfloat16* __restrict__ C) {
  __shared__ __bf16 As[2][256][64];
  __shared__ __bf16 Bs[2][256][64];
  const int t = threadIdx.x, lane = t & 63, w = t >> 6;    // w: 0..7
  const int quad = lane >> 4, low = lane & 15;
  const int wm = w >> 2, wn = w & 3;                       // 2M x 4N waves
  const int m0 = blockIdx.y * 256, n0 = blockIdx.x * 256;

  floatx4 acc[8][4] = {};

  const int srow = t >> 3;                    // 0..63
  const int ssc = ((t & 7) ^ (srow & 7)) * 8; // pre-swizzled source chunk
  const __hip_bfloat16* gA = A + (size_t)(m0 + srow) * 1024 + ssc;
  const __hip_bfloat16* gB = Wt + (size_t)(n0 + srow) * 1024 + ssc;

#define LA(buf) ((ls_char*)&As[buf][0][0] + w * 1024)
#define LB(buf) ((ls_char*)&Bs[buf][0][0] + w * 1024)
  // A halves follow consumption rows wm*128 + mh*64: A0 = rows {0-63,128-191},
  // A1 = {64-127,192-255}. B halves are contiguous: B0 = rows 0-127, B1 = 128-255.
#define ST_A0(buf, k0) do {                                   \
    gload_lds16(gA + (k0),          LA(buf));                 \
    gload_lds16(gA + (k0) + 131072, LA(buf) + 16384);         \
  } while (0)
#define ST_A1(buf, k0) do {                                   \
    gload_lds16(gA + (k0) + 65536,  LA(buf) + 8192);          \
    gload_lds16(gA + (k0) + 196608, LA(buf) + 24576);         \
  } while (0)
#define ST_B0(buf, k0) do {                                   \
    gload_lds16(gB + (k0),          LB(buf));                 \
    gload_lds16(gB + (k0) + 65536,  LB(buf) + 8192);          \
  } while (0)
#define ST_B1(buf, k0) do {                                   \
    gload_lds16(gB + (k0) + 131072, LB(buf) + 16384);         \
    gload_lds16(gB + (k0) + 196608, LB(buf) + 24576);         \
  } while (0)

#define LDA_HALF(mh) do {                                                     \
    _Pragma("unroll")                                                         \
    for (int mi = 0; mi < 4; mi++) {                                          \
      const int ra = wm * 128 + (mh) * 64 + mi * 16 + low;                    \
      af[mi][0] = *(const bf16x8*)&As[cur][ra][((quad) ^ (ra & 7)) * 8];      \
      af[mi][1] = *(const bf16x8*)&As[cur][ra][((4 + quad) ^ (ra & 7)) * 8];  \
    }                                                                         \
  } while (0)

#define LDB_HALF(dst, nh) do {                                                \
    _Pragma("unroll")                                                         \
    for (int ni = 0; ni < 2; ni++) {                                          \
      const int rb = (nh) * 128 + wn * 32 + ni * 16 + low;                    \
      dst[ni][0] = *(const bf16x8*)&Bs[cur][rb][((quad) ^ (rb & 7)) * 8];     \
      dst[ni][1] = *(const bf16x8*)&Bs[cur][rb][((4 + quad) ^ (rb & 7)) * 8]; \
    }                                                                         \
  } while (0)

#define MFMA_Q(bfr, mh, nh) do {                                              \
    __builtin_amdgcn_s_setprio(1);                                            \
    _Pragma("unroll")                                                         \
    for (int mi = 0; mi < 4; mi++)                                            \
      _Pragma("unroll")                                                       \
      for (int ni = 0; ni < 2; ni++) {                                        \
        acc[(mh)*4+mi][(nh)*2+ni] = __builtin_amdgcn_mfma_f32_16x16x32_bf16(  \
            af[mi][0], bfr[ni][0], acc[(mh)*4+mi][(nh)*2+ni], 0, 0, 0);       \
        acc[(mh)*4+mi][(nh)*2+ni] = __builtin_amdgcn_mfma_f32_16x16x32_bf16(  \
            af[mi][1], bfr[ni][1], acc[(mh)*4+mi][(nh)*2+ni], 0, 0, 0);       \
      }                                                                       \
    __builtin_amdgcn_s_setprio(0);                                            \
  } while (0)

  // prologue: tile 0, issue order == consumption order
  ST_A0(0, 0); ST_B0(0, 0); ST_B1(0, 0); ST_A1(0, 0);

  bf16x8 af[4][2], bA[2][2], bB[2][2];

  for (int kt = 0; kt < 16; kt++) {
    const int cur = kt & 1, nxt = cur ^ 1;
    const int kn = (kt + 1) * 64;
    const bool more = (kt + 1 < 16);

    // P0: needs A0,B0 of tile kt (the 4 oldest outstanding loads)
    VMW(4);
    sbar();
    LDA_HALF(0);
    LDB_HALF(bA, 0);
    if (more) ST_A0(nxt, kn);
    MFMA_Q(bA, 0, 0);

    // P1: needs B1 of tile kt
    if (kt < 15) { VMW(4); } else { VMW(2); }
    sbar();
    LDB_HALF(bB, 1);
    if (more) ST_B0(nxt, kn);
    MFMA_Q(bB, 0, 1);

    // P2: needs A1 of tile kt
    if (kt < 15) { VMW(4); } else { VMW(0); }
    sbar();
    LDA_HALF(1);
    if (more) ST_B1(nxt, kn);
    MFMA_Q(bB, 1, 1);

    // P3: register-carried bA; stage last half of next tile
    sbar();
    if (more) ST_A1(nxt, kn);
    MFMA_Q(bA, 1, 0);
  }
#undef ST_A0
#undef ST_A1
#undef ST_B0
#undef ST_B1
#undef LA
#undef LB
#undef LDA_HALF
#undef LDB_HALF
#undef MFMA_Q

  #pragma unroll
  for (int n4 = 0; n4 < 4; n4++) {
    const int nh = n4 >> 1, ni = n4 & 1;
    const int col = n0 + nh * 128 + wn * 32 + ni * 16 + low;
    const float bb = bias[col];
    #pragma unroll
    for (int mi = 0; mi < 8; mi++) {
      const int row = m0 + wm * 128 + mi * 16 + quad * 4;
      #pragma unroll
      for (int i = 0; i < 4; i++) {
        float vv = fmaxf(acc[mi][n4][i] + bb, 0.f);
        C[(size_t)(row + i) * 4096 + col] = __float2bfloat16(vv);
      }
    }
  }
}

// ---------------------------------------------------------------------------
// out = LayerNorm(a0 [+ a1] [+ bias] + r)*g + b ; optional secondary bf16 out.
// ---------------------------------------------------------------------------
template <int EMIT_BF16, int HAS_A1, int HAS_BIAS>
__global__ __launch_bounds__(256) void add_ln(
    const float* __restrict__ a0, const float* __restrict__ a1,
    const float* __restrict__ r, const float* __restrict__ bias,
    const float* __restrict__ g, const float* __restrict__ bt,
    float* __restrict__ out, __hip_bfloat16* __restrict__ outb) {
  __shared__ float red[16];
  const int tok = blockIdx.x, t = threadIdx.x;
  float4 av = ((const float4*)(a0 + (size_t)tok * E_))[t];
  float4 rv = ((const float4*)(r + (size_t)tok * E_))[t];
  float4 x;
  x.x = av.x + rv.x; x.y = av.y + rv.y; x.z = av.z + rv.z; x.w = av.w + rv.w;
  if (HAS_A1) {
    float4 a2 = ((const float4*)(a1 + (size_t)tok * E_))[t];
    x.x += a2.x; x.y += a2.y; x.z += a2.z; x.w += a2.w;
  }
  if (HAS_BIAS) {
    float4 cv = ((const float4*)bias)[t];
    x.x += cv.x; x.y += cv.y; x.z += cv.z; x.w += cv.w;
  }
  float sum = x.x + x.y + x.z + x.w;
  float ssq = x.x * x.x + x.y * x.y + x.z * x.z + x.w * x.w;
  #pragma unroll
  for (int off = 32; off >= 1; off >>= 1) {
    sum += __shfl_down(sum, off, 64);
    ssq += __shfl_down(ssq, off, 64);
  }
  const int wave = t >> 6;
  if ((t & 63) == 0) { red[wave] = sum; red[4 + wave] = ssq; }
  __syncthreads();
  if (t == 0) {
    float s = red[0] + red[1] + red[2] + red[3];
    float qq = red[4] + red[5] + red[6] + red[7];
    float mu = s * (1.0f / E_);
    red[8] = mu;
    red[9] = qq * (1.0f / E_) - mu * mu;
  }
  __syncthreads();
  const float mu = red[8];
  const float inv = rsqrtf(red[9] + 1e-5f);
  float4 gv = ((const float4*)g)[t];
  float4 bv = ((const float4*)bt)[t];
  float4 o;
  o.x = (x.x - mu) * inv * gv.x + bv.x;
  o.y = (x.y - mu) * inv * gv.y + bv.y;
  o.z = (x.z - mu) * inv * gv.z + bv.z;
  o.w = (x.w - mu) * inv * gv.w + bv.w;
  ((float4*)(out + (size_t)tok * E_))[t] = o;
  if (EMIT_BF16) {
    b4s ob;
    ob.x = __float2bfloat16(o.x); ob.y = __float2bfloat16(o.y);
    ob.z = __float2bfloat16(o.z); ob.w = __float2bfloat16(o.w);
    *(b4s*)(outb + (size_t)tok * E_ + t * 4) = ob;
  }
}

// ---------------------------------------------------------------------------
extern "C" void kernel_launch(void* const* d_in, const int* in_sizes, int n_in,
                              void* d_out, int out_size, void* d_ws, size_t ws_size,
                              hipStream_t stream) {
  const float* queries = (const float*)d_in[0];
  const float* keys    = (const float*)d_in[1];
  const float* values  = (const float*)d_in[2];
  const float* Wq  = (const float*)d_in[4];
  const float* Wk  = (const float*)d_in[5];
  const float* Wv  = (const float*)d_in[6];
  const float* Wfc = (const float*)d_in[7];
  const float* bfc = (const float*)d_in[8];
  const float* W1  = (const float*)d_in[9];
  const float* b1  = (const float*)d_in[10];
  const float* W2  = (const float*)d_in[11];
  const float* b2  = (const float*)d_in[12];
  const float* ln1_g = (const float*)d_in[13];
  const float* ln1_b = (const float*)d_in[14];
  const float* ln2_g = (const float*)d_in[15];
  const float* ln2_b = (const float*)d_in[16];

  const size_t M1 = 1048576;
  float* ws = (float*)d_ws;
  float* P0  = ws;             // 4M fl: split-K partial 0
  float* P1  = ws + 4 * M1;    // 4M fl: split-K partial 1
  float* Hf  = ws + 8 * M1;    // 4M fl
  __hip_bfloat16* bb = (__hip_bfloat16*)(ws + 12 * M1);
  __hip_bfloat16* CTXb = bb;                  //  4M
  __hip_bfloat16* Hb   = bb + 4 * M1;         //  4M
  __hip_bfloat16* Wfcb = bb + 8 * M1;         //  1M
  __hip_bfloat16* W1b  = bb + 9 * M1;         //  4M
  __hip_bfloat16* W2b  = bb + 13 * M1;        //  4M
  // attention temps (17M..37M) alias FF1b (17M..33M): FF1b written after attn
  __hip_bfloat16* Qhi  = bb + 17 * M1;        //  4M
  __hip_bfloat16* Qlo  = bb + 21 * M1;        //  4M
  __hip_bfloat16* Khi  = bb + 25 * M1;        //  4M
  __hip_bfloat16* Klo  = bb + 29 * M1;        //  4M
  __hip_bfloat16* Vtb  = bb + 33 * M1;        //  4M
  __hip_bfloat16* FF1b = bb + 17 * M1;        // 16M (after attention)
  __hip_bfloat16* Whlb = bb + 37 * M1;        // 24K
  float* out = (float*)d_out;

  cast_all<<<9228, 256, 0, stream>>>(Wfc, W1, W2, Wfcb, W1b, W2b,
                                     Wq, Wk, Wv, Whlb);

  qkv_fused<<<dim3(S_ / 64, B_ * H_), 256, 0, stream>>>(
      queries, keys, values, Whlb, Qhi, Qlo, Khi, Klo, Vtb);
  attn_mfma<<<dim3(B_ * H_, S_ / 128), 512, 0, stream>>>(
      Qhi, Qlo, Khi, Klo, Vtb, CTXb);
  gemm_mfma<0, 0, 1><<<dim3(E_ / 128, TOK / 128, 2), 256, 0, stream>>>(
      CTXb, Wfcb, nullptr, P0, P1, TOK, E_, 512, E_);
  add_ln<1, 1, 1><<<TOK, 256, 0, stream>>>(
      P0, P1, queries, bfc, ln1_g, ln1_b, Hf, Hb);
  gemm_ff1<<<dim3(4 * E_ / 256, TOK / 256), 512, 0, stream>>>(
      Hb, W1b, b1, FF1b);
  gemm_mfma<0, 0, 1><<<dim3(E_ / 128, TOK / 128, 2), 256, 0, stream>>>(
      FF1b, W2b, nullptr, P0, P1, TOK, E_, 2048, 4 * E_);
  add_ln<0, 1, 1><<<TOK, 256, 0, stream>>>(
      P0, P1, Hf, b2, ln2_g, ln2_b, out, nullptr);
}